// Round 14
// baseline (405.443 us; speedup 1.0000x reference)
//
#include <hip/hip_runtime.h>

#define NTOK 8192
#define DD 1024
#define HH 4096
#define EE 8
#define MAXBLK 72
#define MAXBLK64 136

typedef __attribute__((ext_vector_type(8))) short bf16x8;
typedef __attribute__((ext_vector_type(4))) float f32x4;

__device__ __forceinline__ unsigned short f2bf(float f) {
  unsigned u = __builtin_bit_cast(unsigned, f);
  u += 0x7fffu + ((u >> 16) & 1u);  // round-to-nearest-even
  return (unsigned short)(u >> 16);
}

union Pack8 {
  unsigned short u[8];
  uint4 v;
};

__device__ __forceinline__ void gload_lds16(const void* g, void* l) {
  __builtin_amdgcn_global_load_lds(
      (const __attribute__((address_space(1))) unsigned int*)g,
      (__attribute__((address_space(3))) unsigned int*)l, 16, 0, 0);
}

// ---------------- transpose+convert body: [R][C] f32 tile -> [C][R] bf16 ----------------
__device__ __forceinline__ void trcvt_body(const float* __restrict__ src0,
                                           unsigned short* __restrict__ dst0,
                                           int R, int C, int r0, int c0,
                                           unsigned short* t) {
  const int tid = threadIdx.x;
  const float* src = src0 + (size_t)r0 * C + c0;
  unsigned short* dst = dst0 + (size_t)c0 * R + r0;
#pragma unroll
  for (int it = 0; it < 4; ++it) {
    const int r = it * 16 + (tid >> 4), c4 = (tid & 15) * 4;
    const float4 v = *reinterpret_cast<const float4*>(src + (size_t)r * C + c4);
    t[r * 66 + c4 + 0] = f2bf(v.x);
    t[r * 66 + c4 + 1] = f2bf(v.y);
    t[r * 66 + c4 + 2] = f2bf(v.z);
    t[r * 66 + c4 + 3] = f2bf(v.w);
  }
  __syncthreads();
#pragma unroll
  for (int it = 0; it < 2; ++it) {
    const int cc = it * 32 + (tid >> 3), r8 = (tid & 7) * 8;
    Pack8 p;
#pragma unroll
    for (int j = 0; j < 8; ++j) p.u[j] = t[(r8 + j) * 66 + cc];
    *reinterpret_cast<uint4*>(dst + (size_t)cc * R + r8) = p.v;
  }
}

// ---------------- FAT 1: router (blocks 0..2047) || W1 transpose (blocks 2048..10239) ----------------
__global__ __launch_bounds__(256) void k_rtr1(
    const float* __restrict__ x, const float* __restrict__ Wr,
    const float* __restrict__ br, float* __restrict__ probs,
    float* __restrict__ idxf, int* __restrict__ idxi,
    unsigned short* __restrict__ xb,
    const float* __restrict__ W1, unsigned short* __restrict__ W1t) {
  __shared__ __align__(16) unsigned short SH[64 * 66];
  const int bid = blockIdx.x;
  if (bid < NTOK / 4) {
    const int lane = threadIdx.x & 63;
    const int token = bid * 4 + (threadIdx.x >> 6);
    const float* xr = x + (size_t)token * DD;

    float acc[EE];
#pragma unroll
    for (int e = 0; e < EE; ++e) acc[e] = 0.f;

#pragma unroll
    for (int i = 0; i < 4; ++i) {
      const int d0 = i * 256 + lane * 4;
      const float4 xv = *reinterpret_cast<const float4*>(xr + d0);
      union { unsigned short u[4]; uint2 v; } pk;
      pk.u[0] = f2bf(xv.x); pk.u[1] = f2bf(xv.y);
      pk.u[2] = f2bf(xv.z); pk.u[3] = f2bf(xv.w);
      *reinterpret_cast<uint2*>(xb + (size_t)token * DD + d0) = pk.v;
      const float xs[4] = {xv.x, xv.y, xv.z, xv.w};
#pragma unroll
      for (int j = 0; j < 4; ++j) {
        const float xd = xs[j];
        const float4 w0 = *reinterpret_cast<const float4*>(Wr + (size_t)(d0 + j) * EE);
        const float4 w1 = *reinterpret_cast<const float4*>(Wr + (size_t)(d0 + j) * EE + 4);
        acc[0] += xd * w0.x; acc[1] += xd * w0.y; acc[2] += xd * w0.z; acc[3] += xd * w0.w;
        acc[4] += xd * w1.x; acc[5] += xd * w1.y; acc[6] += xd * w1.z; acc[7] += xd * w1.w;
      }
    }
#pragma unroll
    for (int s = 32; s > 0; s >>= 1) {
#pragma unroll
      for (int e = 0; e < EE; ++e) acc[e] += __shfl_xor(acc[e], s, 64);
    }

    float lg[EE];
#pragma unroll
    for (int e = 0; e < EE; ++e) lg[e] = acc[e] + br[e];

    int best = 0;
    float bv = lg[0];
#pragma unroll
    for (int e = 1; e < EE; ++e) {
      if (lg[e] > bv) { bv = lg[e]; best = e; }  // strict > = numpy first-max
    }
    float p[EE], s = 0.f;
#pragma unroll
    for (int e = 0; e < EE; ++e) { p[e] = expf(lg[e] - bv); s += p[e]; }
    const float inv = 1.f / s;

    if (lane == 0) {
#pragma unroll
      for (int e = 0; e < EE; ++e) probs[(size_t)token * EE + e] = p[e] * inv;
      idxf[token] = (float)best;
      idxi[token] = best;
    }
  } else {
    const int t = bid - NTOK / 4;          // [0, 8192)
    const int e = t >> 10;
    const int rem = t & 1023;
    const int c0 = (rem & 63) * 64;        // col in H
    const int r0 = (rem >> 6) * 64;        // row in D
    trcvt_body(W1 + (size_t)e * DD * HH, W1t + (size_t)e * DD * HH, DD, HH, r0, c0, SH);
  }
}

// ------------- Stable compaction + block tables (128-row and 64-row) -------------
__global__ __launch_bounds__(512) void k_compact(const int* __restrict__ idxi,
                                                 int* __restrict__ cnt,
                                                 int* __restrict__ off,
                                                 int* __restrict__ sorted,
                                                 int* __restrict__ meta) {
  __shared__ int sidx[NTOK];
  __shared__ int scnt[EE], soff[EE];
  const int tid = threadIdx.x;
  for (int i = tid; i < NTOK; i += 512) sidx[i] = idxi[i];
  __syncthreads();
  const int w = tid >> 6, lane = tid & 63;
  if (w < EE) {
    int c = 0;
    for (int i = 0; i < NTOK / 64; ++i) {
      unsigned long long m = __ballot(sidx[i * 64 + lane] == w);
      c += __popcll(m);
    }
    if (lane == 0) scnt[w] = c;
  }
  __syncthreads();
  if (tid == 0) {
    int s = 0;
    for (int e = 0; e < EE; ++e) { soff[e] = s; s += scnt[e]; }
    int nb = 0;
    for (int e = 0; e < EE; ++e) {
      const int nmb = (scnt[e] + 127) >> 7;
      for (int m = 0; m < nmb; ++m) {
        meta[16 + nb] = e;       // 128-row blocks
        meta[96 + nb] = m << 7;
        ++nb;
      }
    }
    meta[0] = nb;
    int nb64 = 0;
    for (int e = 0; e < EE; ++e) {
      const int nmb = (scnt[e] + 63) >> 6;
      for (int m = 0; m < nmb; ++m) {
        meta[176 + nb64] = e;    // 64-row blocks (wave-GEMM)
        meta[320 + nb64] = m << 6;
        ++nb64;
      }
    }
    meta[1] = nb64;
  }
  __syncthreads();
  if (w < EE) {
    int base = soff[w];
    const unsigned long long ltmask = (1ull << lane) - 1ull;
    for (int i = 0; i < NTOK / 64; ++i) {
      const int tok = i * 64 + lane;
      const bool f = (sidx[tok] == w);
      unsigned long long m = __ballot(f);
      if (f) {
        int r = __popcll(m & ltmask);
        sorted[base + r] = tok;
      }
      base += __popcll(m);
    }
    if (lane == 0) { cnt[w] = scnt[w]; off[w] = soff[w]; }
  }
}

// ---------------- standalone transpose (fallback path for W2) ----------------
__global__ __launch_bounds__(256) void k_trcvt64(const float* __restrict__ in,
                                                 unsigned short* __restrict__ outp,
                                                 int R, int C) {
  __shared__ unsigned short t[64 * 66];
  const int e = blockIdx.z;
  trcvt_body(in + (size_t)e * R * C, outp + (size_t)e * R * C, R, C,
             blockIdx.y * 64, blockIdx.x * 64, t);
}

// ---- FAT 2: GEMM1 (y < MAXBLK) || W2 transpose (y >= MAXBLK; only when grid extends) ----
__global__ __launch_bounds__(256) void k_g1tr2(
    const unsigned short* __restrict__ xb, const unsigned short* __restrict__ W1t,
    const float* __restrict__ b1, const int* __restrict__ meta,
    const int* __restrict__ cnt, const int* __restrict__ off,
    const int* __restrict__ sorted, unsigned short* __restrict__ h,
    const float* __restrict__ W2, unsigned short* __restrict__ W2t) {
  __shared__ __align__(16) unsigned short SH[2 * 128 * 64];  // 32 KB
  if (blockIdx.y >= MAXBLK) {
    const int t = (blockIdx.y - MAXBLK) * 32 + blockIdx.x;  // [0, 8192)
    const int e = t >> 10;
    const int rem = t & 1023;
    const int c0 = (rem & 15) * 64;        // col in D
    const int r0 = (rem >> 4) * 64;        // row in H
    trcvt_body(W2 + (size_t)e * HH * DD, W2t + (size_t)e * HH * DD, HH, DD, r0, c0, SH);
    return;
  }
  const int bid = blockIdx.y;
  if (bid >= meta[0]) return;
  const int e = meta[16 + bid];
  const int m0 = meta[96 + bid];
  const int c = cnt[e], base = off[e];
  const int n0 = blockIdx.x * 128;

  unsigned short* Al = SH;
  unsigned short* Bl = SH + 128 * 64;

  const int tid = threadIdx.x, l = tid & 63, w = tid >> 6;

  const unsigned short* aptr[4];
  const unsigned short* bptr[4];
  int soff4[4];
#pragma unroll
  for (int i = 0; i < 4; ++i) {
    const int r = i * 32 + w * 8 + (l >> 3);
    const int swz = ((l & 7) ^ (r & 7)) * 8;
    int ar = m0 + r; if (ar >= c) ar = c - 1;
    const int tok = sorted[base + ar];
    aptr[i] = xb + (size_t)tok * DD + swz;
    bptr[i] = W1t + ((size_t)e * HH + n0 + r) * DD + swz;
    soff4[i] = r * 64 + (l & 7) * 8;
  }

  const int lr = l & 15, lg = l >> 4;
  const int wr = w >> 1, wc = w & 1;
  int aoff[4], boff[4], asw[4], bsw[4];
#pragma unroll
  for (int m = 0; m < 4; ++m) {
    int row = wr * 64 + m * 16 + lr;
    aoff[m] = row * 64; asw[m] = row & 7;
    row = wc * 64 + m * 16 + lr;
    boff[m] = row * 64; bsw[m] = row & 7;
  }

  f32x4 acc[4][4];
#pragma unroll
  for (int m = 0; m < 4; ++m)
#pragma unroll
    for (int n = 0; n < 4; ++n) acc[m][n] = {0.f, 0.f, 0.f, 0.f};

  for (int k0 = 0; k0 < DD; k0 += 64) {
    __syncthreads();
#pragma unroll
    for (int i = 0; i < 4; ++i) gload_lds16(aptr[i] + k0, &Al[soff4[i]]);
#pragma unroll
    for (int i = 0; i < 4; ++i) gload_lds16(bptr[i] + k0, &Bl[soff4[i]]);
    __syncthreads();
#pragma unroll
    for (int ks = 0; ks < 2; ++ks) {
      bf16x8 af[4], bv[4];
#pragma unroll
      for (int m = 0; m < 4; ++m)
        af[m] = *reinterpret_cast<const bf16x8*>(&Al[aoff[m] + (((ks * 4 + lg) ^ asw[m]) * 8)]);
#pragma unroll
      for (int n = 0; n < 4; ++n)
        bv[n] = *reinterpret_cast<const bf16x8*>(&Bl[boff[n] + (((ks * 4 + lg) ^ bsw[n]) * 8)]);
#pragma unroll
      for (int m = 0; m < 4; ++m)
#pragma unroll
        for (int n = 0; n < 4; ++n)
          acc[m][n] = __builtin_amdgcn_mfma_f32_16x16x32_bf16(af[m], bv[n], acc[m][n], 0, 0, 0);
    }
  }

  const int valid = c - m0;
#pragma unroll
  for (int m = 0; m < 4; ++m) {
#pragma unroll
    for (int rr = 0; rr < 4; ++rr) {
      const int tr = wr * 64 + m * 16 + lg * 4 + rr;
      if (tr < valid) {
        const size_t row = (size_t)(base + m0 + tr);
#pragma unroll
        for (int n = 0; n < 4; ++n) {
          const int col = n0 + wc * 64 + n * 16 + lr;
          const float v = acc[m][n][rr] + b1[e * HH + col];
          h[row * HH + col] = f2bf(fmaxf(v, 0.f));
        }
      }
    }
  }
}

// ---- GEMM2 wave version: 64-thread blocks, 64x64 tile, NO barriers ----
// Per wave: private 2x(A+B) LDS dbuf; counted vmcnt(16) (16 loads per tile in flight);
// schedule: vmcnt -> ds_read + 32 MFMA -> sched_barrier -> issue stage(t+2).
__global__ __launch_bounds__(64) void k_gemm2w(
    const unsigned short* __restrict__ h, const unsigned short* __restrict__ W2t,
    const float* __restrict__ b2, const int* __restrict__ meta,
    const int* __restrict__ cnt, const int* __restrict__ off,
    const int* __restrict__ sorted, float* __restrict__ out) {
  const int bid = blockIdx.y;
  if (bid >= meta[1]) return;
  const int e = meta[176 + bid];
  const int m0 = meta[320 + bid];
  const int c = cnt[e], base = off[e];
  const int n0 = blockIdx.x * 64;

  __shared__ __align__(16) unsigned short A0[64 * 64];
  __shared__ __align__(16) unsigned short A1[64 * 64];
  __shared__ __align__(16) unsigned short B0[64 * 64];
  __shared__ __align__(16) unsigned short B1[64 * 64];

  const int l = threadIdx.x;  // 0..63 (one wave)

  const unsigned short* aptr[8];
  const unsigned short* bptr[8];
  int soff[8];
#pragma unroll
  for (int i = 0; i < 8; ++i) {
    const int r = i * 8 + (l >> 3);
    const int swz = ((l & 7) ^ (r & 7)) * 8;  // pre-swizzled source (R9 geometry)
    int ar = m0 + r; if (ar >= c) ar = c - 1;
    aptr[i] = h + (size_t)(base + ar) * HH + swz;
    bptr[i] = W2t + ((size_t)e * DD + n0 + r) * HH + swz;
    soff[i] = r * 64 + (l & 7) * 8;           // wave-linear LDS dest (base + lane*16B)
  }

  const int lr = l & 15, lg = l >> 4;
  int foff[4], fsw[4];
#pragma unroll
  for (int m = 0; m < 4; ++m) {
    const int row = m * 16 + lr;
    foff[m] = row * 64; fsw[m] = row & 7;
  }

  f32x4 acc[4][4];
#pragma unroll
  for (int m = 0; m < 4; ++m)
#pragma unroll
    for (int n = 0; n < 4; ++n) acc[m][n] = {0.f, 0.f, 0.f, 0.f};

#define STGW(Ab, Bb, kk)                                                    \
  {                                                                         \
    _Pragma("unroll") for (int i = 0; i < 8; ++i)                           \
        gload_lds16(aptr[i] + (kk), &Ab[soff[i]]);                          \
    _Pragma("unroll") for (int i = 0; i < 8; ++i)                           \
        gload_lds16(bptr[i] + (kk), &Bb[soff[i]]);                          \
  }

#define CMPW(Ab, Bb)                                                        \
  {                                                                         \
    _Pragma("unroll") for (int ks = 0; ks < 2; ++ks) {                      \
      bf16x8 af[4], bv[4];                                                  \
      _Pragma("unroll") for (int m = 0; m < 4; ++m)                         \
          af[m] = *reinterpret_cast<const bf16x8*>(                         \
              &Ab[foff[m] + (((ks * 4 + lg) ^ fsw[m]) * 8)]);               \
      _Pragma("unroll") for (int n = 0; n < 4; ++n)                         \
          bv[n] = *reinterpret_cast<const bf16x8*>(                         \
              &Bb[foff[n] + (((ks * 4 + lg) ^ fsw[n]) * 8)]);               \
      _Pragma("unroll") for (int m = 0; m < 4; ++m)                         \
          _Pragma("unroll") for (int n = 0; n < 4; ++n)                     \
              acc[m][n] = __builtin_amdgcn_mfma_f32_16x16x32_bf16(          \
                  af[m], bv[n], acc[m][n], 0, 0, 0);                        \
    }                                                                       \
  }

  // prologue: stage tiles 0 and 1 (32 loads in flight)
  STGW(A0, B0, 0);
  STGW(A1, B1, 64);

#pragma unroll 1
  for (int t = 0; t < 62; t += 2) {
    asm volatile("s_waitcnt vmcnt(16)" ::: "memory");  // tile t landed; t+1 in flight
    CMPW(A0, B0);
    __builtin_amdgcn_sched_barrier(0);                 // reads of A0/B0 done before rewrite
    STGW(A0, B0, (t + 2) * 64);
    asm volatile("s_waitcnt vmcnt(16)" ::: "memory");  // tile t+1 landed
    CMPW(A1, B1);
    __builtin_amdgcn_sched_barrier(0);
    STGW(A1, B1, (t + 3) * 64);
  }
  asm volatile("s_waitcnt vmcnt(16)" ::: "memory");  // tile 62 landed
  CMPW(A0, B0);
  asm volatile("s_waitcnt vmcnt(0)" ::: "memory");   // tile 63 landed
  CMPW(A1, B1);

#undef STGW
#undef CMPW

  const int valid = c - m0;
#pragma unroll
  for (int m = 0; m < 4; ++m) {
#pragma unroll
    for (int rr = 0; rr < 4; ++rr) {
      const int tr = m * 16 + lg * 4 + rr;
      if (tr < valid) {
        const int token = sorted[base + m0 + tr];
#pragma unroll
        for (int n = 0; n < 4; ++n) {
          const int col = n0 + n * 16 + lr;
          out[(size_t)token * DD + col] = acc[m][n][rr] + b2[e * DD + col];
        }
      }
    }
  }
}

// ---- GEMM2 fallback (R12): BM=128 BN=64 BK=128 split-LDS, optional split-K ----
template <int KH>
__global__ __launch_bounds__(256) void k_gemm2s(
    const unsigned short* __restrict__ h, const unsigned short* __restrict__ W2t,
    const float* __restrict__ b2, const int* __restrict__ meta,
    const int* __restrict__ cnt, const int* __restrict__ off,
    const int* __restrict__ sorted, float* __restrict__ out,
    float* __restrict__ scr) {
  const int bid = blockIdx.y;
  if (bid >= meta[0]) return;
  const int e = meta[16 + bid];
  const int m0 = meta[96 + bid];
  const int c = cnt[e], base = off[e];
  const int n0 = blockIdx.x * 64;
  const int kh = (KH == 2) ? blockIdx.z : 0;
  const int kbase = kh * (HH / KH);

  __shared__ __align__(16) unsigned short Al0[128 * 64];
  __shared__ __align__(16) unsigned short Al1[128 * 64];
  __shared__ __align__(16) unsigned short Bl0[64 * 64];
  __shared__ __align__(16) unsigned short Bl1[64 * 64];

  const int tid = threadIdx.x, l = tid & 63, w = tid >> 6;

  const unsigned short* aptr[4];
  const unsigned short* bptr[2];
  int asoff[4], bsoff[2];
#pragma unroll
  for (int i = 0; i < 4; ++i) {
    const int r = i * 32 + w * 8 + (l >> 3);
    const int swz = ((l & 7) ^ (r & 7)) * 8;
    int ar = m0 + r; if (ar >= c) ar = c - 1;
    aptr[i] = h + (size_t)(base + ar) * HH + kbase + swz;
    asoff[i] = r * 64 + (l & 7) * 8;
  }
#pragma unroll
  for (int i = 0; i < 2; ++i) {
    const int r = i * 32 + w * 8 + (l >> 3);
    const int swz = ((l & 7) ^ (r & 7)) * 8;
    bptr[i] = W2t + ((size_t)e * DD + n0 + r) * HH + kbase + swz;
    bsoff[i] = r * 64 + (l & 7) * 8;
  }

  const int lr = l & 15, lg = l >> 4;
  const int wr = w >> 1, wc = w & 1;
  int aoff[4], boff[2], asw[4], bsw[2];
#pragma unroll
  for (int m = 0; m < 4; ++m) {
    const int row = wr * 64 + m * 16 + lr;
    aoff[m] = row * 64; asw[m] = row & 7;
  }
#pragma unroll
  for (int n = 0; n < 2; ++n) {
    const int row = wc * 32 + n * 16 + lr;
    boff[n] = row * 64; bsw[n] = row & 7;
  }

  f32x4 acc[4][2];
#pragma unroll
  for (int m = 0; m < 4; ++m)
#pragma unroll
    for (int n = 0; n < 2; ++n) acc[m][n] = {0.f, 0.f, 0.f, 0.f};

  for (int k0 = 0; k0 < HH / KH; k0 += 128) {
    __syncthreads();
#pragma unroll
    for (int i = 0; i < 4; ++i) gload_lds16(aptr[i] + k0, &Al0[asoff[i]]);
#pragma unroll
    for (int i = 0; i < 4; ++i) gload_lds16(aptr[i] + k0 + 64, &Al1[asoff[i]]);
#pragma unroll
    for (int i = 0; i < 2; ++i) gload_lds16(bptr[i] + k0, &Bl0[bsoff[i]]);
#pragma unroll
    for (int i = 0; i < 2; ++i) gload_lds16(bptr[i] + k0 + 64, &Bl1[bsoff[i]]);
    __syncthreads();
#pragma unroll
    for (int ks = 0; ks < 2; ++ks) {
      bf16x8 af[4], bv[2];
#pragma unroll
      for (int m = 0; m < 4; ++m)
        af[m] = *reinterpret_cast<const bf16x8*>(&Al0[aoff[m] + (((ks * 4 + lg) ^ asw[m]) * 8)]);
#pragma unroll
      for (int n = 0; n < 2; ++n)
        bv[n] = *reinterpret_cast<const bf16x8*>(&Bl0[boff[n] + (((ks * 4 + lg) ^ bsw[n]) * 8)]);
#pragma unroll
      for (int m = 0; m < 4; ++m)
#pragma unroll
        for (int n = 0; n < 2; ++n)
          acc[m][n] = __builtin_amdgcn_mfma_f32_16x16x32_bf16(af[m], bv[n], acc[m][n], 0, 0, 0);
    }
#pragma unroll
    for (int ks = 0; ks < 2; ++ks) {
      bf16x8 af[4], bv[2];
#pragma unroll
      for (int m = 0; m < 4; ++m)
        af[m] = *reinterpret_cast<const bf16x8*>(&Al1[aoff[m] + (((ks * 4 + lg) ^ asw[m]) * 8)]);
#pragma unroll
      for (int n = 0; n < 2; ++n)
        bv[n] = *reinterpret_cast<const bf16x8*>(&Bl1[boff[n] + (((ks * 4 + lg) ^ bsw[n]) * 8)]);
#pragma unroll
      for (int m = 0; m < 4; ++m)
#pragma unroll
        for (int n = 0; n < 2; ++n)
          acc[m][n] = __builtin_amdgcn_mfma_f32_16x16x32_bf16(af[m], bv[n], acc[m][n], 0, 0, 0);
    }
  }

  float* dst = (KH == 2 && blockIdx.z == 1) ? scr : out;
  const int valid = c - m0;
#pragma unroll
  for (int m = 0; m < 4; ++m) {
#pragma unroll
    for (int rr = 0; rr < 4; ++rr) {
      const int tr = wr * 64 + m * 16 + lg * 4 + rr;
      if (tr < valid) {
        const int token = sorted[base + m0 + tr];
#pragma unroll
        for (int n = 0; n < 2; ++n) {
          const int col = n0 + wc * 32 + n * 16 + lr;
          float v = acc[m][n][rr];
          if (KH == 1) v += b2[e * DD + col];
          dst[(size_t)token * DD + col] = v;
        }
      }
    }
  }
}

// ---------------- split-K reduce (fallback): out = out + scr + b2[idx[token]] ----------------
__global__ __launch_bounds__(256) void k_reduce2(float* __restrict__ out,
                                                 const float* __restrict__ scr,
                                                 const float* __restrict__ b2,
                                                 const int* __restrict__ idxi) {
  const size_t f = (size_t)blockIdx.x * 256 + threadIdx.x;  // float4 index
  const int token = (int)(f >> 8);
  const int d4 = ((int)f & 255) * 4;
  const int e = idxi[token];
  const float4 a = *reinterpret_cast<const float4*>(out + f * 4);
  const float4 b = *reinterpret_cast<const float4*>(scr + f * 4);
  const float4 bb = *reinterpret_cast<const float4*>(b2 + (size_t)e * DD + d4);
  float4 r;
  r.x = a.x + b.x + bb.x;
  r.y = a.y + b.y + bb.y;
  r.z = a.z + b.z + bb.z;
  r.w = a.w + b.w + bb.w;
  *reinterpret_cast<float4*>(out + f * 4) = r;
}

extern "C" void kernel_launch(void* const* d_in, const int* in_sizes, int n_in,
                              void* d_out, int out_size, void* d_ws, size_t ws_size,
                              hipStream_t stream) {
  const float* x  = (const float*)d_in[0];
  const float* Wr = (const float*)d_in[1];
  const float* br = (const float*)d_in[2];
  const float* W1 = (const float*)d_in[3];
  const float* b1 = (const float*)d_in[4];
  const float* W2 = (const float*)d_in[5];
  const float* b2 = (const float*)d_in[6];

  float* out   = (float*)d_out;
  float* probs = out + (size_t)NTOK * DD;
  float* idxf  = probs + (size_t)NTOK * EE;

  char* ws = (char*)d_ws;
  int* cnt    = (int*)(ws + 0);
  int* off    = (int*)(ws + 64);
  int* meta   = (int*)(ws + 128);      // [0]=nb128 [1]=nb64; e128@16 m128@96 e64@176 m64@320
  int* idxi   = (int*)(ws + 2176);
  int* sorted = (int*)(ws + 34944);

  const size_t OFF_XB   = 67712;                                  // 16 MB
  const size_t OFF_W1T  = OFF_XB + (size_t)NTOK * DD * 2;         // +64 MB
  const size_t OFF_H    = OFF_W1T + (size_t)EE * DD * HH * 2;     // +64 MB
  const size_t OFF_SCR  = OFF_H + (size_t)NTOK * HH * 2;          // +32 MB
  const size_t OFF_W2TB = OFF_SCR + (size_t)NTOK * DD * 4;        // +64 MB (big path)
  const size_t NEED_SPLIT = OFF_W2TB;
  const size_t NEED_BIG   = OFF_W2TB + (size_t)EE * DD * HH * 2;

  unsigned short* xb  = (unsigned short*)(ws + OFF_XB);
  unsigned short* W1t = (unsigned short*)(ws + OFF_W1T);
  unsigned short* h   = (unsigned short*)(ws + OFF_H);
  float*          scr = (float*)(ws + OFF_SCR);

  // FAT1: router || W1-transpose
  k_rtr1<<<NTOK / 4 + 8192, 256, 0, stream>>>(x, Wr, br, probs, idxf, idxi, xb, W1, W1t);
  k_compact<<<1, 512, 0, stream>>>(idxi, cnt, off, sorted, meta);

  if (ws_size >= NEED_BIG) {
    unsigned short* W2t = (unsigned short*)(ws + OFF_W2TB);
    // FAT2: gemm1 || W2-transpose (independent buffers)
    k_g1tr2<<<dim3(HH / 128, MAXBLK + 256), 256, 0, stream>>>(
        xb, W1t, b1, meta, cnt, off, sorted, h, W2, W2t);
    // barrier-free wave GEMM (no split-K, no reduce)
    k_gemm2w<<<dim3(DD / 64, MAXBLK64), 64, 0, stream>>>(
        h, W2t, b2, meta, cnt, off, sorted, out);
  } else if (ws_size >= NEED_SPLIT) {
    unsigned short* W2t = (unsigned short*)(ws + OFF_XB);  // overlay: xb dead after gemm1
    k_g1tr2<<<dim3(HH / 128, MAXBLK), 256, 0, stream>>>(
        xb, W1t, b1, meta, cnt, off, sorted, h, W2, W2t);
    k_trcvt64<<<dim3(DD / 64, HH / 64, EE), 256, 0, stream>>>(W2, W2t, HH, DD);
    k_gemm2s<2><<<dim3(DD / 64, MAXBLK, 2), 256, 0, stream>>>(
        h, W2t, b2, meta, cnt, off, sorted, out, scr);
    k_reduce2<<<(NTOK * DD) / (256 * 4), 256, 0, stream>>>(out, scr, b2, idxi);
  } else {
    unsigned short* W2t = (unsigned short*)(ws + OFF_XB);
    k_g1tr2<<<dim3(HH / 128, MAXBLK), 256, 0, stream>>>(
        xb, W1t, b1, meta, cnt, off, sorted, h, W2, W2t);
    k_trcvt64<<<dim3(DD / 64, HH / 64, EE), 256, 0, stream>>>(W2, W2t, HH, DD);
    k_gemm2s<1><<<dim3(DD / 64, MAXBLK, 1), 256, 0, stream>>>(
        h, W2t, b2, meta, cnt, off, sorted, out, scr);
  }
}

// Round 15
// 374.389 us; speedup vs baseline: 1.0829x; 1.0829x over previous
//
#include <hip/hip_runtime.h>

#define NTOK 8192
#define DD 1024
#define HH 4096
#define EE 8
#define MAXBLK 72

typedef __attribute__((ext_vector_type(8))) short bf16x8;
typedef __attribute__((ext_vector_type(4))) float f32x4;

__device__ __forceinline__ unsigned short f2bf(float f) {
  unsigned u = __builtin_bit_cast(unsigned, f);
  u += 0x7fffu + ((u >> 16) & 1u);  // round-to-nearest-even
  return (unsigned short)(u >> 16);
}

union Pack8 {
  unsigned short u[8];
  uint4 v;
};

__device__ __forceinline__ void gload_lds16(const void* g, void* l) {
  __builtin_amdgcn_global_load_lds(
      (const __attribute__((address_space(1))) unsigned int*)g,
      (__attribute__((address_space(3))) unsigned int*)l, 16, 0, 0);
}

// ---------------- transpose+convert body: [R][C] f32 tile -> [C][R] bf16 ----------------
__device__ __forceinline__ void trcvt_body(const float* __restrict__ src0,
                                           unsigned short* __restrict__ dst0,
                                           int R, int C, int r0, int c0,
                                           unsigned short* t) {
  const int tid = threadIdx.x;
  const float* src = src0 + (size_t)r0 * C + c0;
  unsigned short* dst = dst0 + (size_t)c0 * R + r0;
#pragma unroll
  for (int it = 0; it < 4; ++it) {
    const int r = it * 16 + (tid >> 4), c4 = (tid & 15) * 4;
    const float4 v = *reinterpret_cast<const float4*>(src + (size_t)r * C + c4);
    t[r * 66 + c4 + 0] = f2bf(v.x);
    t[r * 66 + c4 + 1] = f2bf(v.y);
    t[r * 66 + c4 + 2] = f2bf(v.z);
    t[r * 66 + c4 + 3] = f2bf(v.w);
  }
  __syncthreads();
#pragma unroll
  for (int it = 0; it < 2; ++it) {
    const int cc = it * 32 + (tid >> 3), r8 = (tid & 7) * 8;
    Pack8 p;
#pragma unroll
    for (int j = 0; j < 8; ++j) p.u[j] = t[(r8 + j) * 66 + cc];
    *reinterpret_cast<uint4*>(dst + (size_t)cc * R + r8) = p.v;
  }
}

// ---------------- FAT 1: router (blocks 0..2047) || W1 transpose (blocks 2048..10239) ----------------
__global__ __launch_bounds__(256) void k_rtr1(
    const float* __restrict__ x, const float* __restrict__ Wr,
    const float* __restrict__ br, float* __restrict__ probs,
    float* __restrict__ idxf, int* __restrict__ idxi,
    unsigned short* __restrict__ xb,
    const float* __restrict__ W1, unsigned short* __restrict__ W1t) {
  __shared__ __align__(16) unsigned short SH[64 * 66];
  const int bid = blockIdx.x;
  if (bid < NTOK / 4) {
    // ---- router + fused x->bf16 ----
    const int lane = threadIdx.x & 63;
    const int token = bid * 4 + (threadIdx.x >> 6);
    const float* xr = x + (size_t)token * DD;

    float acc[EE];
#pragma unroll
    for (int e = 0; e < EE; ++e) acc[e] = 0.f;

#pragma unroll
    for (int i = 0; i < 4; ++i) {
      const int d0 = i * 256 + lane * 4;
      const float4 xv = *reinterpret_cast<const float4*>(xr + d0);
      union { unsigned short u[4]; uint2 v; } pk;
      pk.u[0] = f2bf(xv.x); pk.u[1] = f2bf(xv.y);
      pk.u[2] = f2bf(xv.z); pk.u[3] = f2bf(xv.w);
      *reinterpret_cast<uint2*>(xb + (size_t)token * DD + d0) = pk.v;
      const float xs[4] = {xv.x, xv.y, xv.z, xv.w};
#pragma unroll
      for (int j = 0; j < 4; ++j) {
        const float xd = xs[j];
        const float4 w0 = *reinterpret_cast<const float4*>(Wr + (size_t)(d0 + j) * EE);
        const float4 w1 = *reinterpret_cast<const float4*>(Wr + (size_t)(d0 + j) * EE + 4);
        acc[0] += xd * w0.x; acc[1] += xd * w0.y; acc[2] += xd * w0.z; acc[3] += xd * w0.w;
        acc[4] += xd * w1.x; acc[5] += xd * w1.y; acc[6] += xd * w1.z; acc[7] += xd * w1.w;
      }
    }
#pragma unroll
    for (int s = 32; s > 0; s >>= 1) {
#pragma unroll
      for (int e = 0; e < EE; ++e) acc[e] += __shfl_xor(acc[e], s, 64);
    }

    float lg[EE];
#pragma unroll
    for (int e = 0; e < EE; ++e) lg[e] = acc[e] + br[e];

    int best = 0;
    float bv = lg[0];
#pragma unroll
    for (int e = 1; e < EE; ++e) {
      if (lg[e] > bv) { bv = lg[e]; best = e; }  // strict > = numpy first-max
    }
    float p[EE], s = 0.f;
#pragma unroll
    for (int e = 0; e < EE; ++e) { p[e] = expf(lg[e] - bv); s += p[e]; }
    const float inv = 1.f / s;

    if (lane == 0) {
#pragma unroll
      for (int e = 0; e < EE; ++e) probs[(size_t)token * EE + e] = p[e] * inv;
      idxf[token] = (float)best;
      idxi[token] = best;
    }
  } else {
    // ---- W1 [E][D][H] -> W1t [E][H][D] (64x64 tile) ----
    const int t = bid - NTOK / 4;          // [0, 8192)
    const int e = t >> 10;
    const int rem = t & 1023;
    const int c0 = (rem & 63) * 64;        // col in H
    const int r0 = (rem >> 6) * 64;        // row in D
    trcvt_body(W1 + (size_t)e * DD * HH, W1t + (size_t)e * DD * HH, DD, HH, r0, c0, SH);
  }
}

// ------------- Stable compaction + block table -------------
__global__ __launch_bounds__(512) void k_compact(const int* __restrict__ idxi,
                                                 int* __restrict__ cnt,
                                                 int* __restrict__ off,
                                                 int* __restrict__ sorted,
                                                 int* __restrict__ meta) {
  __shared__ int sidx[NTOK];
  __shared__ int scnt[EE], soff[EE];
  const int tid = threadIdx.x;
  for (int i = tid; i < NTOK; i += 512) sidx[i] = idxi[i];
  __syncthreads();
  const int w = tid >> 6, lane = tid & 63;
  if (w < EE) {
    int c = 0;
    for (int i = 0; i < NTOK / 64; ++i) {
      unsigned long long m = __ballot(sidx[i * 64 + lane] == w);
      c += __popcll(m);
    }
    if (lane == 0) scnt[w] = c;
  }
  __syncthreads();
  if (tid == 0) {
    int s = 0;
    for (int e = 0; e < EE; ++e) { soff[e] = s; s += scnt[e]; }
    int nb = 0;
    for (int e = 0; e < EE; ++e) {
      const int nmb = (scnt[e] + 127) >> 7;
      for (int m = 0; m < nmb; ++m) {
        meta[16 + nb] = e;
        meta[96 + nb] = m << 7;
        ++nb;
      }
    }
    meta[0] = nb;
  }
  __syncthreads();
  if (w < EE) {
    int base = soff[w];
    const unsigned long long ltmask = (1ull << lane) - 1ull;
    for (int i = 0; i < NTOK / 64; ++i) {
      const int tok = i * 64 + lane;
      const bool f = (sidx[tok] == w);
      unsigned long long m = __ballot(f);
      if (f) {
        int r = __popcll(m & ltmask);
        sorted[base + r] = tok;
      }
      base += __popcll(m);
    }
    if (lane == 0) { cnt[w] = scnt[w]; off[w] = soff[w]; }
  }
}

// ---------------- standalone transpose (fallback path for W2) ----------------
__global__ __launch_bounds__(256) void k_trcvt64(const float* __restrict__ in,
                                                 unsigned short* __restrict__ outp,
                                                 int R, int C) {
  __shared__ unsigned short t[64 * 66];
  const int e = blockIdx.z;
  trcvt_body(in + (size_t)e * R * C, outp + (size_t)e * R * C, R, C,
             blockIdx.y * 64, blockIdx.x * 64, t);
}

// ---- FAT 2: GEMM1 (y < MAXBLK) || W2 transpose (y >= MAXBLK; only when grid extends) ----
// GEMM1: h = relu(xb_sel @ W1t^T + b1) -> bf16. grid.x = HH/128 N-blocks.
__global__ __launch_bounds__(256) void k_g1tr2(
    const unsigned short* __restrict__ xb, const unsigned short* __restrict__ W1t,
    const float* __restrict__ b1, const int* __restrict__ meta,
    const int* __restrict__ cnt, const int* __restrict__ off,
    const int* __restrict__ sorted, unsigned short* __restrict__ h,
    const float* __restrict__ W2, unsigned short* __restrict__ W2t) {
  __shared__ __align__(16) unsigned short SH[2 * 128 * 64];  // 32 KB (transpose uses 8.4 KB)
  if (blockIdx.y >= MAXBLK) {
    // ---- W2 [E][H][D] -> W2t [E][D][H] (64x64 tile) ----
    const int t = (blockIdx.y - MAXBLK) * 32 + blockIdx.x;  // [0, 8192)
    const int e = t >> 10;
    const int rem = t & 1023;
    const int c0 = (rem & 15) * 64;        // col in D
    const int r0 = (rem >> 4) * 64;        // row in H
    trcvt_body(W2 + (size_t)e * HH * DD, W2t + (size_t)e * HH * DD, HH, DD, r0, c0, SH);
    return;
  }
  const int bid = blockIdx.y;
  if (bid >= meta[0]) return;
  const int e = meta[16 + bid];
  const int m0 = meta[96 + bid];
  const int c = cnt[e], base = off[e];
  const int n0 = blockIdx.x * 128;

  unsigned short* Al = SH;
  unsigned short* Bl = SH + 128 * 64;

  const int tid = threadIdx.x, l = tid & 63, w = tid >> 6;

  const unsigned short* aptr[4];
  const unsigned short* bptr[4];
  int soff4[4];
#pragma unroll
  for (int i = 0; i < 4; ++i) {
    const int r = i * 32 + w * 8 + (l >> 3);
    const int swz = ((l & 7) ^ (r & 7)) * 8;  // pre-swizzled global source
    int ar = m0 + r; if (ar >= c) ar = c - 1;
    const int tok = sorted[base + ar];
    aptr[i] = xb + (size_t)tok * DD + swz;
    bptr[i] = W1t + ((size_t)e * HH + n0 + r) * DD + swz;
    soff4[i] = r * 64 + (l & 7) * 8;
  }

  const int lr = l & 15, lg = l >> 4;
  const int wr = w >> 1, wc = w & 1;
  int aoff[4], boff[4], asw[4], bsw[4];
#pragma unroll
  for (int m = 0; m < 4; ++m) {
    int row = wr * 64 + m * 16 + lr;
    aoff[m] = row * 64; asw[m] = row & 7;
    row = wc * 64 + m * 16 + lr;
    boff[m] = row * 64; bsw[m] = row & 7;
  }

  f32x4 acc[4][4];
#pragma unroll
  for (int m = 0; m < 4; ++m)
#pragma unroll
    for (int n = 0; n < 4; ++n) acc[m][n] = {0.f, 0.f, 0.f, 0.f};

  for (int k0 = 0; k0 < DD; k0 += 64) {
    __syncthreads();
#pragma unroll
    for (int i = 0; i < 4; ++i) gload_lds16(aptr[i] + k0, &Al[soff4[i]]);
#pragma unroll
    for (int i = 0; i < 4; ++i) gload_lds16(bptr[i] + k0, &Bl[soff4[i]]);
    __syncthreads();
#pragma unroll
    for (int ks = 0; ks < 2; ++ks) {
      bf16x8 af[4], bv[4];
#pragma unroll
      for (int m = 0; m < 4; ++m)
        af[m] = *reinterpret_cast<const bf16x8*>(&Al[aoff[m] + (((ks * 4 + lg) ^ asw[m]) * 8)]);
#pragma unroll
      for (int n = 0; n < 4; ++n)
        bv[n] = *reinterpret_cast<const bf16x8*>(&Bl[boff[n] + (((ks * 4 + lg) ^ bsw[n]) * 8)]);
#pragma unroll
      for (int m = 0; m < 4; ++m)
#pragma unroll
        for (int n = 0; n < 4; ++n)
          acc[m][n] = __builtin_amdgcn_mfma_f32_16x16x32_bf16(af[m], bv[n], acc[m][n], 0, 0, 0);
    }
  }

  const int valid = c - m0;
#pragma unroll
  for (int m = 0; m < 4; ++m) {
#pragma unroll
    for (int rr = 0; rr < 4; ++rr) {
      const int tr = wr * 64 + m * 16 + lg * 4 + rr;
      if (tr < valid) {
        const size_t row = (size_t)(base + m0 + tr);
#pragma unroll
        for (int n = 0; n < 4; ++n) {
          const int col = n0 + wc * 64 + n * 16 + lr;
          const float v = acc[m][n][rr] + b1[e * HH + col];
          h[row * HH + col] = f2bf(fmaxf(v, 0.f));
        }
      }
    }
  }
}

// ---- GEMM2: BM=128 BN=64 BK=128 via SPLIT 64-col LDS halves (R12-exact), split-K ----
template <int KH>
__global__ __launch_bounds__(256) void k_gemm2s(
    const unsigned short* __restrict__ h, const unsigned short* __restrict__ W2t,
    const float* __restrict__ b2, const int* __restrict__ meta,
    const int* __restrict__ cnt, const int* __restrict__ off,
    const int* __restrict__ sorted, float* __restrict__ out,
    float* __restrict__ scr) {
  const int bid = blockIdx.y;
  if (bid >= meta[0]) return;
  const int e = meta[16 + bid];
  const int m0 = meta[96 + bid];
  const int c = cnt[e], base = off[e];
  const int n0 = blockIdx.x * 64;
  const int kh = (KH == 2) ? blockIdx.z : 0;
  const int kbase = kh * (HH / KH);

  __shared__ __align__(16) unsigned short Al0[128 * 64];
  __shared__ __align__(16) unsigned short Al1[128 * 64];
  __shared__ __align__(16) unsigned short Bl0[64 * 64];
  __shared__ __align__(16) unsigned short Bl1[64 * 64];

  const int tid = threadIdx.x, l = tid & 63, w = tid >> 6;

  const unsigned short* aptr[4];
  const unsigned short* bptr[2];
  int asoff[4], bsoff[2];
#pragma unroll
  for (int i = 0; i < 4; ++i) {
    const int r = i * 32 + w * 8 + (l >> 3);
    const int swz = ((l & 7) ^ (r & 7)) * 8;
    int ar = m0 + r; if (ar >= c) ar = c - 1;
    aptr[i] = h + (size_t)(base + ar) * HH + kbase + swz;
    asoff[i] = r * 64 + (l & 7) * 8;
  }
#pragma unroll
  for (int i = 0; i < 2; ++i) {
    const int r = i * 32 + w * 8 + (l >> 3);
    const int swz = ((l & 7) ^ (r & 7)) * 8;
    bptr[i] = W2t + ((size_t)e * DD + n0 + r) * HH + kbase + swz;
    bsoff[i] = r * 64 + (l & 7) * 8;
  }

  const int lr = l & 15, lg = l >> 4;
  const int wr = w >> 1, wc = w & 1;
  int aoff[4], boff[2], asw[4], bsw[2];
#pragma unroll
  for (int m = 0; m < 4; ++m) {
    const int row = wr * 64 + m * 16 + lr;
    aoff[m] = row * 64; asw[m] = row & 7;
  }
#pragma unroll
  for (int n = 0; n < 2; ++n) {
    const int row = wc * 32 + n * 16 + lr;
    boff[n] = row * 64; bsw[n] = row & 7;
  }

  f32x4 acc[4][2];
#pragma unroll
  for (int m = 0; m < 4; ++m)
#pragma unroll
    for (int n = 0; n < 2; ++n) acc[m][n] = {0.f, 0.f, 0.f, 0.f};

  for (int k0 = 0; k0 < HH / KH; k0 += 128) {
    __syncthreads();
#pragma unroll
    for (int i = 0; i < 4; ++i) gload_lds16(aptr[i] + k0, &Al0[asoff[i]]);
#pragma unroll
    for (int i = 0; i < 4; ++i) gload_lds16(aptr[i] + k0 + 64, &Al1[asoff[i]]);
#pragma unroll
    for (int i = 0; i < 2; ++i) gload_lds16(bptr[i] + k0, &Bl0[bsoff[i]]);
#pragma unroll
    for (int i = 0; i < 2; ++i) gload_lds16(bptr[i] + k0 + 64, &Bl1[bsoff[i]]);
    __syncthreads();
#pragma unroll
    for (int ks = 0; ks < 2; ++ks) {
      bf16x8 af[4], bv[2];
#pragma unroll
      for (int m = 0; m < 4; ++m)
        af[m] = *reinterpret_cast<const bf16x8*>(&Al0[aoff[m] + (((ks * 4 + lg) ^ asw[m]) * 8)]);
#pragma unroll
      for (int n = 0; n < 2; ++n)
        bv[n] = *reinterpret_cast<const bf16x8*>(&Bl0[boff[n] + (((ks * 4 + lg) ^ bsw[n]) * 8)]);
#pragma unroll
      for (int m = 0; m < 4; ++m)
#pragma unroll
        for (int n = 0; n < 2; ++n)
          acc[m][n] = __builtin_amdgcn_mfma_f32_16x16x32_bf16(af[m], bv[n], acc[m][n], 0, 0, 0);
    }
#pragma unroll
    for (int ks = 0; ks < 2; ++ks) {
      bf16x8 af[4], bv[2];
#pragma unroll
      for (int m = 0; m < 4; ++m)
        af[m] = *reinterpret_cast<const bf16x8*>(&Al1[aoff[m] + (((ks * 4 + lg) ^ asw[m]) * 8)]);
#pragma unroll
      for (int n = 0; n < 2; ++n)
        bv[n] = *reinterpret_cast<const bf16x8*>(&Bl1[boff[n] + (((ks * 4 + lg) ^ bsw[n]) * 8)]);
#pragma unroll
      for (int m = 0; m < 4; ++m)
#pragma unroll
        for (int n = 0; n < 2; ++n)
          acc[m][n] = __builtin_amdgcn_mfma_f32_16x16x32_bf16(af[m], bv[n], acc[m][n], 0, 0, 0);
    }
  }

  float* dst = (KH == 2 && blockIdx.z == 1) ? scr : out;
  const int valid = c - m0;
#pragma unroll
  for (int m = 0; m < 4; ++m) {
#pragma unroll
    for (int rr = 0; rr < 4; ++rr) {
      const int tr = wr * 64 + m * 16 + lg * 4 + rr;
      if (tr < valid) {
        const int token = sorted[base + m0 + tr];
#pragma unroll
        for (int n = 0; n < 2; ++n) {
          const int col = n0 + wc * 32 + n * 16 + lr;
          float v = acc[m][n][rr];
          if (KH == 1) v += b2[e * DD + col];
          dst[(size_t)token * DD + col] = v;
        }
      }
    }
  }
}

// ---------------- split-K reduce: out = out + scr + b2[idx[token]] ----------------
__global__ __launch_bounds__(256) void k_reduce2(float* __restrict__ out,
                                                 const float* __restrict__ scr,
                                                 const float* __restrict__ b2,
                                                 const int* __restrict__ idxi) {
  const size_t f = (size_t)blockIdx.x * 256 + threadIdx.x;  // float4 index
  const int token = (int)(f >> 8);
  const int d4 = ((int)f & 255) * 4;
  const int e = idxi[token];
  const float4 a = *reinterpret_cast<const float4*>(out + f * 4);
  const float4 b = *reinterpret_cast<const float4*>(scr + f * 4);
  const float4 bb = *reinterpret_cast<const float4*>(b2 + (size_t)e * DD + d4);
  float4 r;
  r.x = a.x + b.x + bb.x;
  r.y = a.y + b.y + bb.y;
  r.z = a.z + b.z + bb.z;
  r.w = a.w + b.w + bb.w;
  *reinterpret_cast<float4*>(out + f * 4) = r;
}

extern "C" void kernel_launch(void* const* d_in, const int* in_sizes, int n_in,
                              void* d_out, int out_size, void* d_ws, size_t ws_size,
                              hipStream_t stream) {
  const float* x  = (const float*)d_in[0];
  const float* Wr = (const float*)d_in[1];
  const float* br = (const float*)d_in[2];
  const float* W1 = (const float*)d_in[3];
  const float* b1 = (const float*)d_in[4];
  const float* W2 = (const float*)d_in[5];
  const float* b2 = (const float*)d_in[6];

  float* out   = (float*)d_out;
  float* probs = out + (size_t)NTOK * DD;
  float* idxf  = probs + (size_t)NTOK * EE;

  char* ws = (char*)d_ws;
  int* cnt    = (int*)(ws + 0);
  int* off    = (int*)(ws + 64);
  int* meta   = (int*)(ws + 128);      // [0]=nblk, [16..]=blk_e, [96..]=blk_m0
  int* idxi   = (int*)(ws + 1024);
  int* sorted = (int*)(ws + 33792);

  const size_t OFF_XB   = 66560;                                  // 16 MB
  const size_t OFF_W1T  = OFF_XB + (size_t)NTOK * DD * 2;         // +64 MB
  const size_t OFF_H    = OFF_W1T + (size_t)EE * DD * HH * 2;     // +64 MB
  const size_t OFF_SCR  = OFF_H + (size_t)NTOK * HH * 2;          // +32 MB
  const size_t OFF_W2TB = OFF_SCR + (size_t)NTOK * DD * 4;        // +64 MB (big path)
  const size_t NEED_SPLIT = OFF_W2TB;                              // 184,615,936
  const size_t NEED_BIG   = OFF_W2TB + (size_t)EE * DD * HH * 2;  // 251,724,800

  unsigned short* xb  = (unsigned short*)(ws + OFF_XB);
  unsigned short* W1t = (unsigned short*)(ws + OFF_W1T);
  unsigned short* h   = (unsigned short*)(ws + OFF_H);
  float*          scr = (float*)(ws + OFF_SCR);

  // FAT1: router || W1-transpose
  k_rtr1<<<NTOK / 4 + 8192, 256, 0, stream>>>(x, Wr, br, probs, idxf, idxi, xb, W1, W1t);
  k_compact<<<1, 512, 0, stream>>>(idxi, cnt, off, sorted, meta);

  if (ws_size >= NEED_BIG) {
    unsigned short* W2t = (unsigned short*)(ws + OFF_W2TB);
    // FAT2: gemm1 || W2-transpose (independent buffers)
    k_g1tr2<<<dim3(HH / 128, MAXBLK + 256), 256, 0, stream>>>(
        xb, W1t, b1, meta, cnt, off, sorted, h, W2, W2t);
    k_gemm2s<2><<<dim3(DD / 64, MAXBLK, 2), 256, 0, stream>>>(
        h, W2t, b2, meta, cnt, off, sorted, out, scr);
    k_reduce2<<<(NTOK * DD) / (256 * 4), 256, 0, stream>>>(out, scr, b2, idxi);
  } else if (ws_size >= NEED_SPLIT) {
    unsigned short* W2t = (unsigned short*)(ws + OFF_XB);  // overlay: xb dead after gemm1
    k_g1tr2<<<dim3(HH / 128, MAXBLK), 256, 0, stream>>>(
        xb, W1t, b1, meta, cnt, off, sorted, h, W2, W2t);
    k_trcvt64<<<dim3(DD / 64, HH / 64, EE), 256, 0, stream>>>(W2, W2t, HH, DD);
    k_gemm2s<2><<<dim3(DD / 64, MAXBLK, 2), 256, 0, stream>>>(
        h, W2t, b2, meta, cnt, off, sorted, out, scr);
    k_reduce2<<<(NTOK * DD) / (256 * 4), 256, 0, stream>>>(out, scr, b2, idxi);
  } else {
    unsigned short* W2t = (unsigned short*)(ws + OFF_XB);
    k_g1tr2<<<dim3(HH / 128, MAXBLK), 256, 0, stream>>>(
        xb, W1t, b1, meta, cnt, off, sorted, h, W2, W2t);
    k_trcvt64<<<dim3(DD / 64, HH / 64, EE), 256, 0, stream>>>(W2, W2t, HH, DD);
    k_gemm2s<1><<<dim3(DD / 64, MAXBLK, 1), 256, 0, stream>>>(
        h, W2t, b2, meta, cnt, off, sorted, out, scr);
  }
}

// Round 16
// 372.421 us; speedup vs baseline: 1.0887x; 1.0053x over previous
//
#include <hip/hip_runtime.h>

#define NTOK 8192
#define DD 1024
#define HH 4096
#define EE 8
#define MAXBLK 72

typedef __attribute__((ext_vector_type(8))) short bf16x8;
typedef __attribute__((ext_vector_type(4))) float f32x4;

__device__ __forceinline__ unsigned short f2bf(float f) {
  unsigned u = __builtin_bit_cast(unsigned, f);
  u += 0x7fffu + ((u >> 16) & 1u);  // round-to-nearest-even
  return (unsigned short)(u >> 16);
}

union Pack8 {
  unsigned short u[8];
  uint4 v;
};

__device__ __forceinline__ void gload_lds16(const void* g, void* l) {
  __builtin_amdgcn_global_load_lds(
      (const __attribute__((address_space(1))) unsigned int*)g,
      (__attribute__((address_space(3))) unsigned int*)l, 16, 0, 0);
}

// ---------------- transpose+convert body: [R][C] f32 tile -> [C][R] bf16 ----------------
__device__ __forceinline__ void trcvt_body(const float* __restrict__ src0,
                                           unsigned short* __restrict__ dst0,
                                           int R, int C, int r0, int c0,
                                           unsigned short* t) {
  const int tid = threadIdx.x;
  const float* src = src0 + (size_t)r0 * C + c0;
  unsigned short* dst = dst0 + (size_t)c0 * R + r0;
#pragma unroll
  for (int it = 0; it < 4; ++it) {
    const int r = it * 16 + (tid >> 4), c4 = (tid & 15) * 4;
    const float4 v = *reinterpret_cast<const float4*>(src + (size_t)r * C + c4);
    t[r * 66 + c4 + 0] = f2bf(v.x);
    t[r * 66 + c4 + 1] = f2bf(v.y);
    t[r * 66 + c4 + 2] = f2bf(v.z);
    t[r * 66 + c4 + 3] = f2bf(v.w);
  }
  __syncthreads();
#pragma unroll
  for (int it = 0; it < 2; ++it) {
    const int cc = it * 32 + (tid >> 3), r8 = (tid & 7) * 8;
    Pack8 p;
#pragma unroll
    for (int j = 0; j < 8; ++j) p.u[j] = t[(r8 + j) * 66 + cc];
    *reinterpret_cast<uint4*>(dst + (size_t)cc * R + r8) = p.v;
  }
}

// ---------------- FAT 1: router (blocks 0..2047) || W1 transpose (blocks 2048..10239) ----------------
__global__ __launch_bounds__(256) void k_rtr1(
    const float* __restrict__ x, const float* __restrict__ Wr,
    const float* __restrict__ br, float* __restrict__ probs,
    float* __restrict__ idxf, int* __restrict__ idxi,
    unsigned short* __restrict__ xb,
    const float* __restrict__ W1, unsigned short* __restrict__ W1t) {
  __shared__ __align__(16) unsigned short SH[64 * 66];
  const int bid = blockIdx.x;
  if (bid < NTOK / 4) {
    // ---- router + fused x->bf16 ----
    const int lane = threadIdx.x & 63;
    const int token = bid * 4 + (threadIdx.x >> 6);
    const float* xr = x + (size_t)token * DD;

    float acc[EE];
#pragma unroll
    for (int e = 0; e < EE; ++e) acc[e] = 0.f;

#pragma unroll
    for (int i = 0; i < 4; ++i) {
      const int d0 = i * 256 + lane * 4;
      const float4 xv = *reinterpret_cast<const float4*>(xr + d0);
      union { unsigned short u[4]; uint2 v; } pk;
      pk.u[0] = f2bf(xv.x); pk.u[1] = f2bf(xv.y);
      pk.u[2] = f2bf(xv.z); pk.u[3] = f2bf(xv.w);
      *reinterpret_cast<uint2*>(xb + (size_t)token * DD + d0) = pk.v;
      const float xs[4] = {xv.x, xv.y, xv.z, xv.w};
#pragma unroll
      for (int j = 0; j < 4; ++j) {
        const float xd = xs[j];
        const float4 w0 = *reinterpret_cast<const float4*>(Wr + (size_t)(d0 + j) * EE);
        const float4 w1 = *reinterpret_cast<const float4*>(Wr + (size_t)(d0 + j) * EE + 4);
        acc[0] += xd * w0.x; acc[1] += xd * w0.y; acc[2] += xd * w0.z; acc[3] += xd * w0.w;
        acc[4] += xd * w1.x; acc[5] += xd * w1.y; acc[6] += xd * w1.z; acc[7] += xd * w1.w;
      }
    }
#pragma unroll
    for (int s = 32; s > 0; s >>= 1) {
#pragma unroll
      for (int e = 0; e < EE; ++e) acc[e] += __shfl_xor(acc[e], s, 64);
    }

    float lg[EE];
#pragma unroll
    for (int e = 0; e < EE; ++e) lg[e] = acc[e] + br[e];

    int best = 0;
    float bv = lg[0];
#pragma unroll
    for (int e = 1; e < EE; ++e) {
      if (lg[e] > bv) { bv = lg[e]; best = e; }  // strict > = numpy first-max
    }
    float p[EE], s = 0.f;
#pragma unroll
    for (int e = 0; e < EE; ++e) { p[e] = expf(lg[e] - bv); s += p[e]; }
    const float inv = 1.f / s;

    if (lane == 0) {
#pragma unroll
      for (int e = 0; e < EE; ++e) probs[(size_t)token * EE + e] = p[e] * inv;
      idxf[token] = (float)best;
      idxi[token] = best;
    }
  } else {
    // ---- W1 [E][D][H] -> W1t [E][H][D] (64x64 tile) ----
    const int t = bid - NTOK / 4;          // [0, 8192)
    const int e = t >> 10;
    const int rem = t & 1023;
    const int c0 = (rem & 63) * 64;        // col in H
    const int r0 = (rem >> 6) * 64;        // row in D
    trcvt_body(W1 + (size_t)e * DD * HH, W1t + (size_t)e * DD * HH, DD, HH, r0, c0, SH);
  }
}

// ------------- Stable compaction + block table -------------
__global__ __launch_bounds__(512) void k_compact(const int* __restrict__ idxi,
                                                 int* __restrict__ cnt,
                                                 int* __restrict__ off,
                                                 int* __restrict__ sorted,
                                                 int* __restrict__ meta) {
  __shared__ int sidx[NTOK];
  __shared__ int scnt[EE], soff[EE];
  const int tid = threadIdx.x;
  for (int i = tid; i < NTOK; i += 512) sidx[i] = idxi[i];
  __syncthreads();
  const int w = tid >> 6, lane = tid & 63;
  if (w < EE) {
    int c = 0;
    for (int i = 0; i < NTOK / 64; ++i) {
      unsigned long long m = __ballot(sidx[i * 64 + lane] == w);
      c += __popcll(m);
    }
    if (lane == 0) scnt[w] = c;
  }
  __syncthreads();
  if (tid == 0) {
    int s = 0;
    for (int e = 0; e < EE; ++e) { soff[e] = s; s += scnt[e]; }
    int nb = 0;
    for (int e = 0; e < EE; ++e) {
      const int nmb = (scnt[e] + 127) >> 7;
      for (int m = 0; m < nmb; ++m) {
        meta[16 + nb] = e;
        meta[96 + nb] = m << 7;
        ++nb;
      }
    }
    meta[0] = nb;
  }
  __syncthreads();
  if (w < EE) {
    int base = soff[w];
    const unsigned long long ltmask = (1ull << lane) - 1ull;
    for (int i = 0; i < NTOK / 64; ++i) {
      const int tok = i * 64 + lane;
      const bool f = (sidx[tok] == w);
      unsigned long long m = __ballot(f);
      if (f) {
        int r = __popcll(m & ltmask);
        sorted[base + r] = tok;
      }
      base += __popcll(m);
    }
    if (lane == 0) { cnt[w] = scnt[w]; off[w] = soff[w]; }
  }
}

// ---------------- standalone transpose (fallback path for W2) ----------------
__global__ __launch_bounds__(256) void k_trcvt64(const float* __restrict__ in,
                                                 unsigned short* __restrict__ outp,
                                                 int R, int C) {
  __shared__ unsigned short t[64 * 66];
  const int e = blockIdx.z;
  trcvt_body(in + (size_t)e * R * C, outp + (size_t)e * R * C, R, C,
             blockIdx.y * 64, blockIdx.x * 64, t);
}

// ---- FAT 2: GEMM1 (y < MAXBLK) || W2 transpose (y >= MAXBLK; only when grid extends) ----
// GEMM1: h = relu(xb_sel @ W1t^T + b1) -> bf16. grid.x = HH/128 N-blocks.
__global__ __launch_bounds__(256) void k_g1tr2(
    const unsigned short* __restrict__ xb, const unsigned short* __restrict__ W1t,
    const float* __restrict__ b1, const int* __restrict__ meta,
    const int* __restrict__ cnt, const int* __restrict__ off,
    const int* __restrict__ sorted, unsigned short* __restrict__ h,
    const float* __restrict__ W2, unsigned short* __restrict__ W2t) {
  __shared__ __align__(16) unsigned short SH[2 * 128 * 64];  // 32 KB (transpose uses 8.4 KB)
  if (blockIdx.y >= MAXBLK) {
    // ---- W2 [E][H][D] -> W2t [E][D][H] (64x64 tile) ----
    const int t = (blockIdx.y - MAXBLK) * 32 + blockIdx.x;  // [0, 8192)
    const int e = t >> 10;
    const int rem = t & 1023;
    const int c0 = (rem & 15) * 64;        // col in D
    const int r0 = (rem >> 4) * 64;        // row in H
    trcvt_body(W2 + (size_t)e * HH * DD, W2t + (size_t)e * HH * DD, HH, DD, r0, c0, SH);
    return;
  }
  const int bid = blockIdx.y;
  if (bid >= meta[0]) return;
  const int e = meta[16 + bid];
  const int m0 = meta[96 + bid];
  const int c = cnt[e], base = off[e];
  const int n0 = blockIdx.x * 128;

  unsigned short* Al = SH;
  unsigned short* Bl = SH + 128 * 64;

  const int tid = threadIdx.x, l = tid & 63, w = tid >> 6;

  const unsigned short* aptr[4];
  const unsigned short* bptr[4];
  int soff4[4];
#pragma unroll
  for (int i = 0; i < 4; ++i) {
    const int r = i * 32 + w * 8 + (l >> 3);
    const int swz = ((l & 7) ^ (r & 7)) * 8;  // pre-swizzled global source
    int ar = m0 + r; if (ar >= c) ar = c - 1;
    const int tok = sorted[base + ar];
    aptr[i] = xb + (size_t)tok * DD + swz;
    bptr[i] = W1t + ((size_t)e * HH + n0 + r) * DD + swz;
    soff4[i] = r * 64 + (l & 7) * 8;
  }

  const int lr = l & 15, lg = l >> 4;
  const int wr = w >> 1, wc = w & 1;
  int aoff[4], boff[4], asw[4], bsw[4];
#pragma unroll
  for (int m = 0; m < 4; ++m) {
    int row = wr * 64 + m * 16 + lr;
    aoff[m] = row * 64; asw[m] = row & 7;
    row = wc * 64 + m * 16 + lr;
    boff[m] = row * 64; bsw[m] = row & 7;
  }

  f32x4 acc[4][4];
#pragma unroll
  for (int m = 0; m < 4; ++m)
#pragma unroll
    for (int n = 0; n < 4; ++n) acc[m][n] = {0.f, 0.f, 0.f, 0.f};

  for (int k0 = 0; k0 < DD; k0 += 64) {
    __syncthreads();
#pragma unroll
    for (int i = 0; i < 4; ++i) gload_lds16(aptr[i] + k0, &Al[soff4[i]]);
#pragma unroll
    for (int i = 0; i < 4; ++i) gload_lds16(bptr[i] + k0, &Bl[soff4[i]]);
    __syncthreads();
#pragma unroll
    for (int ks = 0; ks < 2; ++ks) {
      bf16x8 af[4], bv[4];
#pragma unroll
      for (int m = 0; m < 4; ++m)
        af[m] = *reinterpret_cast<const bf16x8*>(&Al[aoff[m] + (((ks * 4 + lg) ^ asw[m]) * 8)]);
#pragma unroll
      for (int n = 0; n < 4; ++n)
        bv[n] = *reinterpret_cast<const bf16x8*>(&Bl[boff[n] + (((ks * 4 + lg) ^ bsw[n]) * 8)]);
#pragma unroll
      for (int m = 0; m < 4; ++m)
#pragma unroll
        for (int n = 0; n < 4; ++n)
          acc[m][n] = __builtin_amdgcn_mfma_f32_16x16x32_bf16(af[m], bv[n], acc[m][n], 0, 0, 0);
    }
  }

  const int valid = c - m0;
#pragma unroll
  for (int m = 0; m < 4; ++m) {
#pragma unroll
    for (int rr = 0; rr < 4; ++rr) {
      const int tr = wr * 64 + m * 16 + lg * 4 + rr;
      if (tr < valid) {
        const size_t row = (size_t)(base + m0 + tr);
#pragma unroll
        for (int n = 0; n < 4; ++n) {
          const int col = n0 + wc * 64 + n * 16 + lr;
          const float v = acc[m][n][rr] + b1[e * HH + col];
          h[row * HH + col] = f2bf(fmaxf(v, 0.f));
        }
      }
    }
  }
}

// ---- GEMM2: BM=128 BN=64 BK=64, LDS DOUBLE-BUFFER + counted vmcnt(6), split-K ----
// Per K-step: STAGE(next buf, 6 loads) -> vmcnt(6) [waits prev tile only; 6 stay in
// flight across both barriers] -> barrier -> compute (16 MFMA/wave) -> barrier.
// 48 KB LDS -> 3 blocks/CU; grid 2304 blocks (16 N x 72 M x 2 kh). Static buffers.
template <int KH>
__global__ __launch_bounds__(256) void k_gemm2d(
    const unsigned short* __restrict__ h, const unsigned short* __restrict__ W2t,
    const float* __restrict__ b2, const int* __restrict__ meta,
    const int* __restrict__ cnt, const int* __restrict__ off,
    const int* __restrict__ sorted, float* __restrict__ out,
    float* __restrict__ scr) {
  const int bid = blockIdx.y;
  if (bid >= meta[0]) return;
  const int e = meta[16 + bid];
  const int m0 = meta[96 + bid];
  const int c = cnt[e], base = off[e];
  const int n0 = blockIdx.x * 64;
  const int kh = (KH == 2) ? blockIdx.z : 0;
  const int kbase = kh * (HH / KH);

  __shared__ __align__(16) unsigned short A0[128 * 64];  // 16 KB
  __shared__ __align__(16) unsigned short A1[128 * 64];  // 16 KB
  __shared__ __align__(16) unsigned short B0[64 * 64];   // 8 KB
  __shared__ __align__(16) unsigned short B1[64 * 64];   // 8 KB

  const int tid = threadIdx.x, l = tid & 63, w = tid >> 6;

  const unsigned short* aptr[4];
  const unsigned short* bptr[2];
  int asoff[4], bsoff[2];
#pragma unroll
  for (int i = 0; i < 4; ++i) {
    const int r = i * 32 + w * 8 + (l >> 3);
    const int swz = ((l & 7) ^ (r & 7)) * 8;  // pre-swizzled source (R9 0-conflict geometry)
    int ar = m0 + r; if (ar >= c) ar = c - 1;
    aptr[i] = h + (size_t)(base + ar) * HH + kbase + swz;
    asoff[i] = r * 64 + (l & 7) * 8;          // wave-linear LDS dest
  }
#pragma unroll
  for (int i = 0; i < 2; ++i) {
    const int r = i * 32 + w * 8 + (l >> 3);
    const int swz = ((l & 7) ^ (r & 7)) * 8;
    bptr[i] = W2t + ((size_t)e * DD + n0 + r) * HH + kbase + swz;
    bsoff[i] = r * 64 + (l & 7) * 8;
  }

  const int lr = l & 15, lg = l >> 4;
  const int wr = w >> 1, wc = w & 1;
  int aoff[4], boff[2], asw[4], bsw[2];
#pragma unroll
  for (int m = 0; m < 4; ++m) {
    const int row = wr * 64 + m * 16 + lr;
    aoff[m] = row * 64; asw[m] = row & 7;
  }
#pragma unroll
  for (int n = 0; n < 2; ++n) {
    const int row = wc * 32 + n * 16 + lr;
    boff[n] = row * 64; bsw[n] = row & 7;
  }

  f32x4 acc[4][2];
#pragma unroll
  for (int m = 0; m < 4; ++m)
#pragma unroll
    for (int n = 0; n < 2; ++n) acc[m][n] = {0.f, 0.f, 0.f, 0.f};

#define STG2(Ab, Bb, kk)                                                    \
  {                                                                         \
    _Pragma("unroll") for (int i = 0; i < 4; ++i)                           \
        gload_lds16(aptr[i] + (kk), &Ab[asoff[i]]);                         \
    _Pragma("unroll") for (int i = 0; i < 2; ++i)                           \
        gload_lds16(bptr[i] + (kk), &Bb[bsoff[i]]);                         \
  }

#define CMP2(Ab, Bb)                                                        \
  {                                                                         \
    _Pragma("unroll") for (int ks = 0; ks < 2; ++ks) {                      \
      bf16x8 af[4], bv[2];                                                  \
      _Pragma("unroll") for (int m = 0; m < 4; ++m)                         \
          af[m] = *reinterpret_cast<const bf16x8*>(                         \
              &Ab[aoff[m] + (((ks * 4 + lg) ^ asw[m]) * 8)]);               \
      _Pragma("unroll") for (int n = 0; n < 2; ++n)                         \
          bv[n] = *reinterpret_cast<const bf16x8*>(                         \
              &Bb[boff[n] + (((ks * 4 + lg) ^ bsw[n]) * 8)]);               \
      _Pragma("unroll") for (int m = 0; m < 4; ++m)                         \
          _Pragma("unroll") for (int n = 0; n < 2; ++n)                     \
              acc[m][n] = __builtin_amdgcn_mfma_f32_16x16x32_bf16(          \
                  af[m], bv[n], acc[m][n], 0, 0, 0);                        \
    }                                                                       \
  }

  const int NT = (HH / KH) / 64;  // 32 (KH=2) or 64 (KH=1); even

  // prologue: tile 0 -> buf0 (6 loads in flight)
  STG2(A0, B0, 0);

#pragma unroll 1
  for (int t2 = 1; t2 + 1 < NT; t2 += 2) {
    STG2(A1, B1, t2 * 64);                              // 12 outstanding
    asm volatile("s_waitcnt vmcnt(6)" ::: "memory");    // tile t2-1 landed; 6 in flight
    __builtin_amdgcn_s_barrier();
    CMP2(A0, B0);                                       // ds_reads complete before next bar
    __builtin_amdgcn_s_barrier();                       // all waves done with buf0
    STG2(A0, B0, (t2 + 1) * 64);
    asm volatile("s_waitcnt vmcnt(6)" ::: "memory");    // tile t2 landed
    __builtin_amdgcn_s_barrier();
    CMP2(A1, B1);
    __builtin_amdgcn_s_barrier();
  }
  // tail: buf0 holds tile NT-2 (in flight); stage final tile NT-1
  STG2(A1, B1, (NT - 1) * 64);
  asm volatile("s_waitcnt vmcnt(6)" ::: "memory");      // tile NT-2 landed
  __builtin_amdgcn_s_barrier();
  CMP2(A0, B0);
  asm volatile("s_waitcnt vmcnt(0)" ::: "memory");      // tile NT-1 landed
  __builtin_amdgcn_s_barrier();
  CMP2(A1, B1);

#undef STG2
#undef CMP2

  float* dst = (KH == 2 && blockIdx.z == 1) ? scr : out;
  const int valid = c - m0;
#pragma unroll
  for (int m = 0; m < 4; ++m) {
#pragma unroll
    for (int rr = 0; rr < 4; ++rr) {
      const int tr = wr * 64 + m * 16 + lg * 4 + rr;
      if (tr < valid) {
        const int token = sorted[base + m0 + tr];
#pragma unroll
        for (int n = 0; n < 2; ++n) {
          const int col = n0 + wc * 32 + n * 16 + lr;
          float v = acc[m][n][rr];
          if (KH == 1) v += b2[e * DD + col];
          dst[(size_t)token * DD + col] = v;
        }
      }
    }
  }
}

// ---------------- split-K reduce: out = out + scr + b2[idx[token]] ----------------
__global__ __launch_bounds__(256) void k_reduce2(float* __restrict__ out,
                                                 const float* __restrict__ scr,
                                                 const float* __restrict__ b2,
                                                 const int* __restrict__ idxi) {
  const size_t f = (size_t)blockIdx.x * 256 + threadIdx.x;  // float4 index
  const int token = (int)(f >> 8);
  const int d4 = ((int)f & 255) * 4;
  const int e = idxi[token];
  const float4 a = *reinterpret_cast<const float4*>(out + f * 4);
  const float4 b = *reinterpret_cast<const float4*>(scr + f * 4);
  const float4 bb = *reinterpret_cast<const float4*>(b2 + (size_t)e * DD + d4);
  float4 r;
  r.x = a.x + b.x + bb.x;
  r.y = a.y + b.y + bb.y;
  r.z = a.z + b.z + bb.z;
  r.w = a.w + b.w + bb.w;
  *reinterpret_cast<float4*>(out + f * 4) = r;
}

extern "C" void kernel_launch(void* const* d_in, const int* in_sizes, int n_in,
                              void* d_out, int out_size, void* d_ws, size_t ws_size,
                              hipStream_t stream) {
  const float* x  = (const float*)d_in[0];
  const float* Wr = (const float*)d_in[1];
  const float* br = (const float*)d_in[2];
  const float* W1 = (const float*)d_in[3];
  const float* b1 = (const float*)d_in[4];
  const float* W2 = (const float*)d_in[5];
  const float* b2 = (const float*)d_in[6];

  float* out   = (float*)d_out;
  float* probs = out + (size_t)NTOK * DD;
  float* idxf  = probs + (size_t)NTOK * EE;

  char* ws = (char*)d_ws;
  int* cnt    = (int*)(ws + 0);
  int* off    = (int*)(ws + 64);
  int* meta   = (int*)(ws + 128);      // [0]=nblk, [16..]=blk_e, [96..]=blk_m0
  int* idxi   = (int*)(ws + 1024);
  int* sorted = (int*)(ws + 33792);

  const size_t OFF_XB   = 66560;                                  // 16 MB
  const size_t OFF_W1T  = OFF_XB + (size_t)NTOK * DD * 2;         // +64 MB
  const size_t OFF_H    = OFF_W1T + (size_t)EE * DD * HH * 2;     // +64 MB
  const size_t OFF_SCR  = OFF_H + (size_t)NTOK * HH * 2;          // +32 MB
  const size_t OFF_W2TB = OFF_SCR + (size_t)NTOK * DD * 4;        // +64 MB (big path)
  const size_t NEED_SPLIT = OFF_W2TB;                              // 184,615,936
  const size_t NEED_BIG   = OFF_W2TB + (size_t)EE * DD * HH * 2;  // 251,724,800

  unsigned short* xb  = (unsigned short*)(ws + OFF_XB);
  unsigned short* W1t = (unsigned short*)(ws + OFF_W1T);
  unsigned short* h   = (unsigned short*)(ws + OFF_H);
  float*          scr = (float*)(ws + OFF_SCR);

  // FAT1: router || W1-transpose
  k_rtr1<<<NTOK / 4 + 8192, 256, 0, stream>>>(x, Wr, br, probs, idxf, idxi, xb, W1, W1t);
  k_compact<<<1, 512, 0, stream>>>(idxi, cnt, off, sorted, meta);

  if (ws_size >= NEED_BIG) {
    unsigned short* W2t = (unsigned short*)(ws + OFF_W2TB);
    // FAT2: gemm1 || W2-transpose (independent buffers)
    k_g1tr2<<<dim3(HH / 128, MAXBLK + 256), 256, 0, stream>>>(
        xb, W1t, b1, meta, cnt, off, sorted, h, W2, W2t);
    k_gemm2d<2><<<dim3(DD / 64, MAXBLK, 2), 256, 0, stream>>>(
        h, W2t, b2, meta, cnt, off, sorted, out, scr);
    k_reduce2<<<(NTOK * DD) / (256 * 4), 256, 0, stream>>>(out, scr, b2, idxi);
  } else if (ws_size >= NEED_SPLIT) {
    unsigned short* W2t = (unsigned short*)(ws + OFF_XB);  // overlay: xb dead after gemm1
    k_g1tr2<<<dim3(HH / 128, MAXBLK), 256, 0, stream>>>(
        xb, W1t, b1, meta, cnt, off, sorted, h, W2, W2t);
    k_trcvt64<<<dim3(DD / 64, HH / 64, EE), 256, 0, stream>>>(W2, W2t, HH, DD);
    k_gemm2d<2><<<dim3(DD / 64, MAXBLK, 2), 256, 0, stream>>>(
        h, W2t, b2, meta, cnt, off, sorted, out, scr);
    k_reduce2<<<(NTOK * DD) / (256 * 4), 256, 0, stream>>>(out, scr, b2, idxi);
  } else {
    unsigned short* W2t = (unsigned short*)(ws + OFF_XB);
    k_g1tr2<<<dim3(HH / 128, MAXBLK), 256, 0, stream>>>(
        xb, W1t, b1, meta, cnt, off, sorted, h, W2, W2t);
    k_trcvt64<<<dim3(DD / 64, HH / 64, EE), 256, 0, stream>>>(W2, W2t, HH, DD);
    k_gemm2d<1><<<dim3(DD / 64, MAXBLK, 1), 256, 0, stream>>>(
        h, W2t, b2, meta, cnt, off, sorted, out, scr);
  }
}

// Round 17
// 353.810 us; speedup vs baseline: 1.1459x; 1.0526x over previous
//
#include <hip/hip_runtime.h>

#define NTOK 8192
#define DD 1024
#define HH 4096
#define EE 8
#define MAXBLK 72

typedef __attribute__((ext_vector_type(8))) short bf16x8;
typedef __attribute__((ext_vector_type(4))) float f32x4;

__device__ __forceinline__ unsigned short f2bf(float f) {
  unsigned u = __builtin_bit_cast(unsigned, f);
  u += 0x7fffu + ((u >> 16) & 1u);  // round-to-nearest-even
  return (unsigned short)(u >> 16);
}

union Pack8 {
  unsigned short u[8];
  uint4 v;
};

__device__ __forceinline__ void gload_lds16(const void* g, void* l) {
  __builtin_amdgcn_global_load_lds(
      (const __attribute__((address_space(1))) unsigned int*)g,
      (__attribute__((address_space(3))) unsigned int*)l, 16, 0, 0);
}

// ---------------- transpose+convert body: [R][C] f32 tile -> [C][R] bf16 ----------------
__device__ __forceinline__ void trcvt_body(const float* __restrict__ src0,
                                           unsigned short* __restrict__ dst0,
                                           int R, int C, int r0, int c0,
                                           unsigned short* t) {
  const int tid = threadIdx.x;
  const float* src = src0 + (size_t)r0 * C + c0;
  unsigned short* dst = dst0 + (size_t)c0 * R + r0;
#pragma unroll
  for (int it = 0; it < 4; ++it) {
    const int r = it * 16 + (tid >> 4), c4 = (tid & 15) * 4;
    const float4 v = *reinterpret_cast<const float4*>(src + (size_t)r * C + c4);
    t[r * 66 + c4 + 0] = f2bf(v.x);
    t[r * 66 + c4 + 1] = f2bf(v.y);
    t[r * 66 + c4 + 2] = f2bf(v.z);
    t[r * 66 + c4 + 3] = f2bf(v.w);
  }
  __syncthreads();
#pragma unroll
  for (int it = 0; it < 2; ++it) {
    const int cc = it * 32 + (tid >> 3), r8 = (tid & 7) * 8;
    Pack8 p;
#pragma unroll
    for (int j = 0; j < 8; ++j) p.u[j] = t[(r8 + j) * 66 + cc];
    *reinterpret_cast<uint4*>(dst + (size_t)cc * R + r8) = p.v;
  }
}

// ---------------- FAT 1: router (blocks 0..2047) || W1 transpose (blocks 2048..10239) ----------------
__global__ __launch_bounds__(256) void k_rtr1(
    const float* __restrict__ x, const float* __restrict__ Wr,
    const float* __restrict__ br, float* __restrict__ probs,
    float* __restrict__ idxf, int* __restrict__ idxi,
    unsigned short* __restrict__ xb,
    const float* __restrict__ W1, unsigned short* __restrict__ W1t) {
  __shared__ __align__(16) unsigned short SH[64 * 66];
  const int bid = blockIdx.x;
  if (bid < NTOK / 4) {
    // ---- router + fused x->bf16 ----
    const int lane = threadIdx.x & 63;
    const int token = bid * 4 + (threadIdx.x >> 6);
    const float* xr = x + (size_t)token * DD;

    float acc[EE];
#pragma unroll
    for (int e = 0; e < EE; ++e) acc[e] = 0.f;

#pragma unroll
    for (int i = 0; i < 4; ++i) {
      const int d0 = i * 256 + lane * 4;
      const float4 xv = *reinterpret_cast<const float4*>(xr + d0);
      union { unsigned short u[4]; uint2 v; } pk;
      pk.u[0] = f2bf(xv.x); pk.u[1] = f2bf(xv.y);
      pk.u[2] = f2bf(xv.z); pk.u[3] = f2bf(xv.w);
      *reinterpret_cast<uint2*>(xb + (size_t)token * DD + d0) = pk.v;
      const float xs[4] = {xv.x, xv.y, xv.z, xv.w};
#pragma unroll
      for (int j = 0; j < 4; ++j) {
        const float xd = xs[j];
        const float4 w0 = *reinterpret_cast<const float4*>(Wr + (size_t)(d0 + j) * EE);
        const float4 w1 = *reinterpret_cast<const float4*>(Wr + (size_t)(d0 + j) * EE + 4);
        acc[0] += xd * w0.x; acc[1] += xd * w0.y; acc[2] += xd * w0.z; acc[3] += xd * w0.w;
        acc[4] += xd * w1.x; acc[5] += xd * w1.y; acc[6] += xd * w1.z; acc[7] += xd * w1.w;
      }
    }
#pragma unroll
    for (int s = 32; s > 0; s >>= 1) {
#pragma unroll
      for (int e = 0; e < EE; ++e) acc[e] += __shfl_xor(acc[e], s, 64);
    }

    float lg[EE];
#pragma unroll
    for (int e = 0; e < EE; ++e) lg[e] = acc[e] + br[e];

    int best = 0;
    float bv = lg[0];
#pragma unroll
    for (int e = 1; e < EE; ++e) {
      if (lg[e] > bv) { bv = lg[e]; best = e; }  // strict > = numpy first-max
    }
    float p[EE], s = 0.f;
#pragma unroll
    for (int e = 0; e < EE; ++e) { p[e] = expf(lg[e] - bv); s += p[e]; }
    const float inv = 1.f / s;

    if (lane == 0) {
#pragma unroll
      for (int e = 0; e < EE; ++e) probs[(size_t)token * EE + e] = p[e] * inv;
      idxf[token] = (float)best;
      idxi[token] = best;
    }
  } else {
    // ---- W1 [E][D][H] -> W1t [E][H][D] (64x64 tile) ----
    const int t = bid - NTOK / 4;          // [0, 8192)
    const int e = t >> 10;
    const int rem = t & 1023;
    const int c0 = (rem & 63) * 64;        // col in H
    const int r0 = (rem >> 6) * 64;        // row in D
    trcvt_body(W1 + (size_t)e * DD * HH, W1t + (size_t)e * DD * HH, DD, HH, r0, c0, SH);
  }
}

// ------------- Stable compaction + block table -------------
__global__ __launch_bounds__(512) void k_compact(const int* __restrict__ idxi,
                                                 int* __restrict__ cnt,
                                                 int* __restrict__ off,
                                                 int* __restrict__ sorted,
                                                 int* __restrict__ meta) {
  __shared__ int sidx[NTOK];
  __shared__ int scnt[EE], soff[EE];
  const int tid = threadIdx.x;
  for (int i = tid; i < NTOK; i += 512) sidx[i] = idxi[i];
  __syncthreads();
  const int w = tid >> 6, lane = tid & 63;
  if (w < EE) {
    int c = 0;
    for (int i = 0; i < NTOK / 64; ++i) {
      unsigned long long m = __ballot(sidx[i * 64 + lane] == w);
      c += __popcll(m);
    }
    if (lane == 0) scnt[w] = c;
  }
  __syncthreads();
  if (tid == 0) {
    int s = 0;
    for (int e = 0; e < EE; ++e) { soff[e] = s; s += scnt[e]; }
    int nb = 0;
    for (int e = 0; e < EE; ++e) {
      const int nmb = (scnt[e] + 127) >> 7;
      for (int m = 0; m < nmb; ++m) {
        meta[16 + nb] = e;
        meta[96 + nb] = m << 7;
        ++nb;
      }
    }
    meta[0] = nb;
  }
  __syncthreads();
  if (w < EE) {
    int base = soff[w];
    const unsigned long long ltmask = (1ull << lane) - 1ull;
    for (int i = 0; i < NTOK / 64; ++i) {
      const int tok = i * 64 + lane;
      const bool f = (sidx[tok] == w);
      unsigned long long m = __ballot(f);
      if (f) {
        int r = __popcll(m & ltmask);
        sorted[base + r] = tok;
      }
      base += __popcll(m);
    }
    if (lane == 0) { cnt[w] = scnt[w]; off[w] = soff[w]; }
  }
}

// ---------------- standalone transpose (fallback path for W2) ----------------
__global__ __launch_bounds__(256) void k_trcvt64(const float* __restrict__ in,
                                                 unsigned short* __restrict__ outp,
                                                 int R, int C) {
  __shared__ unsigned short t[64 * 66];
  const int e = blockIdx.z;
  trcvt_body(in + (size_t)e * R * C, outp + (size_t)e * R * C, R, C,
             blockIdx.y * 64, blockIdx.x * 64, t);
}

// ---- FAT 2: GEMM1 (y < MAXBLK) || W2 transpose (y >= MAXBLK; only when grid extends) ----
// GEMM1: h = relu(xb_sel @ W1t^T + b1) -> bf16. grid.x = HH/128 N-blocks.
__global__ __launch_bounds__(256) void k_g1tr2(
    const unsigned short* __restrict__ xb, const unsigned short* __restrict__ W1t,
    const float* __restrict__ b1, const int* __restrict__ meta,
    const int* __restrict__ cnt, const int* __restrict__ off,
    const int* __restrict__ sorted, unsigned short* __restrict__ h,
    const float* __restrict__ W2, unsigned short* __restrict__ W2t) {
  __shared__ __align__(16) unsigned short SH[2 * 128 * 64];  // 32 KB (transpose uses 8.4 KB)
  if (blockIdx.y >= MAXBLK) {
    // ---- W2 [E][H][D] -> W2t [E][D][H] (64x64 tile) ----
    const int t = (blockIdx.y - MAXBLK) * 32 + blockIdx.x;  // [0, 8192)
    const int e = t >> 10;
    const int rem = t & 1023;
    const int c0 = (rem & 15) * 64;        // col in D
    const int r0 = (rem >> 4) * 64;        // row in H
    trcvt_body(W2 + (size_t)e * HH * DD, W2t + (size_t)e * HH * DD, HH, DD, r0, c0, SH);
    return;
  }
  const int bid = blockIdx.y;
  if (bid >= meta[0]) return;
  const int e = meta[16 + bid];
  const int m0 = meta[96 + bid];
  const int c = cnt[e], base = off[e];
  const int n0 = blockIdx.x * 128;

  unsigned short* Al = SH;
  unsigned short* Bl = SH + 128 * 64;

  const int tid = threadIdx.x, l = tid & 63, w = tid >> 6;

  const unsigned short* aptr[4];
  const unsigned short* bptr[4];
  int soff4[4];
#pragma unroll
  for (int i = 0; i < 4; ++i) {
    const int r = i * 32 + w * 8 + (l >> 3);
    const int swz = ((l & 7) ^ (r & 7)) * 8;  // pre-swizzled global source
    int ar = m0 + r; if (ar >= c) ar = c - 1;
    const int tok = sorted[base + ar];
    aptr[i] = xb + (size_t)tok * DD + swz;
    bptr[i] = W1t + ((size_t)e * HH + n0 + r) * DD + swz;
    soff4[i] = r * 64 + (l & 7) * 8;
  }

  const int lr = l & 15, lg = l >> 4;
  const int wr = w >> 1, wc = w & 1;
  int aoff[4], boff[4], asw[4], bsw[4];
#pragma unroll
  for (int m = 0; m < 4; ++m) {
    int row = wr * 64 + m * 16 + lr;
    aoff[m] = row * 64; asw[m] = row & 7;
    row = wc * 64 + m * 16 + lr;
    boff[m] = row * 64; bsw[m] = row & 7;
  }

  f32x4 acc[4][4];
#pragma unroll
  for (int m = 0; m < 4; ++m)
#pragma unroll
    for (int n = 0; n < 4; ++n) acc[m][n] = {0.f, 0.f, 0.f, 0.f};

  for (int k0 = 0; k0 < DD; k0 += 64) {
    __syncthreads();
#pragma unroll
    for (int i = 0; i < 4; ++i) gload_lds16(aptr[i] + k0, &Al[soff4[i]]);
#pragma unroll
    for (int i = 0; i < 4; ++i) gload_lds16(bptr[i] + k0, &Bl[soff4[i]]);
    __syncthreads();
#pragma unroll
    for (int ks = 0; ks < 2; ++ks) {
      bf16x8 af[4], bv[4];
#pragma unroll
      for (int m = 0; m < 4; ++m)
        af[m] = *reinterpret_cast<const bf16x8*>(&Al[aoff[m] + (((ks * 4 + lg) ^ asw[m]) * 8)]);
#pragma unroll
      for (int n = 0; n < 4; ++n)
        bv[n] = *reinterpret_cast<const bf16x8*>(&Bl[boff[n] + (((ks * 4 + lg) ^ bsw[n]) * 8)]);
      __builtin_amdgcn_s_setprio(1);
#pragma unroll
      for (int m = 0; m < 4; ++m)
#pragma unroll
        for (int n = 0; n < 4; ++n)
          acc[m][n] = __builtin_amdgcn_mfma_f32_16x16x32_bf16(af[m], bv[n], acc[m][n], 0, 0, 0);
      __builtin_amdgcn_s_setprio(0);
    }
  }

  const int valid = c - m0;
#pragma unroll
  for (int m = 0; m < 4; ++m) {
#pragma unroll
    for (int rr = 0; rr < 4; ++rr) {
      const int tr = wr * 64 + m * 16 + lg * 4 + rr;
      if (tr < valid) {
        const size_t row = (size_t)(base + m0 + tr);
#pragma unroll
        for (int n = 0; n < 4; ++n) {
          const int col = n0 + wc * 64 + n * 16 + lr;
          const float v = acc[m][n][rr] + b1[e * HH + col];
          h[row * HH + col] = f2bf(fmaxf(v, 0.f));
        }
      }
    }
  }
}

// ---- GEMM2: BM=128 BN=64 BK=64, LDS DOUBLE-BUFFER + counted vmcnt(6), split-K ----
// Per K-step: STAGE(next buf, 6 loads) -> vmcnt(6) -> barrier -> compute -> barrier.
// Bias added by kh==0 blocks; kh==1 writes raw partials to scr.
template <int KH>
__global__ __launch_bounds__(256) void k_gemm2d(
    const unsigned short* __restrict__ h, const unsigned short* __restrict__ W2t,
    const float* __restrict__ b2, const int* __restrict__ meta,
    const int* __restrict__ cnt, const int* __restrict__ off,
    const int* __restrict__ sorted, float* __restrict__ out,
    float* __restrict__ scr) {
  const int bid = blockIdx.y;
  if (bid >= meta[0]) return;
  const int e = meta[16 + bid];
  const int m0 = meta[96 + bid];
  const int c = cnt[e], base = off[e];
  const int n0 = blockIdx.x * 64;
  const int kh = (KH == 2) ? blockIdx.z : 0;
  const int kbase = kh * (HH / KH);

  __shared__ __align__(16) unsigned short A0[128 * 64];  // 16 KB
  __shared__ __align__(16) unsigned short A1[128 * 64];  // 16 KB
  __shared__ __align__(16) unsigned short B0[64 * 64];   // 8 KB
  __shared__ __align__(16) unsigned short B1[64 * 64];   // 8 KB

  const int tid = threadIdx.x, l = tid & 63, w = tid >> 6;

  const unsigned short* aptr[4];
  const unsigned short* bptr[2];
  int asoff[4], bsoff[2];
#pragma unroll
  for (int i = 0; i < 4; ++i) {
    const int r = i * 32 + w * 8 + (l >> 3);
    const int swz = ((l & 7) ^ (r & 7)) * 8;  // pre-swizzled source (R9 0-conflict geometry)
    int ar = m0 + r; if (ar >= c) ar = c - 1;
    aptr[i] = h + (size_t)(base + ar) * HH + kbase + swz;
    asoff[i] = r * 64 + (l & 7) * 8;          // wave-linear LDS dest
  }
#pragma unroll
  for (int i = 0; i < 2; ++i) {
    const int r = i * 32 + w * 8 + (l >> 3);
    const int swz = ((l & 7) ^ (r & 7)) * 8;
    bptr[i] = W2t + ((size_t)e * DD + n0 + r) * HH + kbase + swz;
    bsoff[i] = r * 64 + (l & 7) * 8;
  }

  const int lr = l & 15, lg = l >> 4;
  const int wr = w >> 1, wc = w & 1;
  int aoff[4], boff[2], asw[4], bsw[2];
#pragma unroll
  for (int m = 0; m < 4; ++m) {
    const int row = wr * 64 + m * 16 + lr;
    aoff[m] = row * 64; asw[m] = row & 7;
  }
#pragma unroll
  for (int n = 0; n < 2; ++n) {
    const int row = wc * 32 + n * 16 + lr;
    boff[n] = row * 64; bsw[n] = row & 7;
  }

  f32x4 acc[4][2];
#pragma unroll
  for (int m = 0; m < 4; ++m)
#pragma unroll
    for (int n = 0; n < 2; ++n) acc[m][n] = {0.f, 0.f, 0.f, 0.f};

#define STG2(Ab, Bb, kk)                                                    \
  {                                                                         \
    _Pragma("unroll") for (int i = 0; i < 4; ++i)                           \
        gload_lds16(aptr[i] + (kk), &Ab[asoff[i]]);                         \
    _Pragma("unroll") for (int i = 0; i < 2; ++i)                           \
        gload_lds16(bptr[i] + (kk), &Bb[bsoff[i]]);                         \
  }

#define CMP2(Ab, Bb)                                                        \
  {                                                                         \
    _Pragma("unroll") for (int ks = 0; ks < 2; ++ks) {                      \
      bf16x8 af[4], bv[2];                                                  \
      _Pragma("unroll") for (int m = 0; m < 4; ++m)                         \
          af[m] = *reinterpret_cast<const bf16x8*>(                         \
              &Ab[aoff[m] + (((ks * 4 + lg) ^ asw[m]) * 8)]);               \
      _Pragma("unroll") for (int n = 0; n < 2; ++n)                         \
          bv[n] = *reinterpret_cast<const bf16x8*>(                         \
              &Bb[boff[n] + (((ks * 4 + lg) ^ bsw[n]) * 8)]);               \
      __builtin_amdgcn_s_setprio(1);                                        \
      _Pragma("unroll") for (int m = 0; m < 4; ++m)                         \
          _Pragma("unroll") for (int n = 0; n < 2; ++n)                     \
              acc[m][n] = __builtin_amdgcn_mfma_f32_16x16x32_bf16(          \
                  af[m], bv[n], acc[m][n], 0, 0, 0);                        \
      __builtin_amdgcn_s_setprio(0);                                        \
    }                                                                       \
  }

  const int NT = (HH / KH) / 64;  // 32 (KH=2) or 64 (KH=1); even

  // prologue: tile 0 -> buf0 (6 loads in flight)
  STG2(A0, B0, 0);

#pragma unroll 1
  for (int t2 = 1; t2 + 1 < NT; t2 += 2) {
    STG2(A1, B1, t2 * 64);                              // 12 outstanding
    asm volatile("s_waitcnt vmcnt(6)" ::: "memory");    // tile t2-1 landed; 6 in flight
    __builtin_amdgcn_s_barrier();
    CMP2(A0, B0);
    __builtin_amdgcn_s_barrier();                       // all waves done with buf0
    STG2(A0, B0, (t2 + 1) * 64);
    asm volatile("s_waitcnt vmcnt(6)" ::: "memory");    // tile t2 landed
    __builtin_amdgcn_s_barrier();
    CMP2(A1, B1);
    __builtin_amdgcn_s_barrier();
  }
  // tail: buf0 holds tile NT-2 (in flight); stage final tile NT-1
  STG2(A1, B1, (NT - 1) * 64);
  asm volatile("s_waitcnt vmcnt(6)" ::: "memory");      // tile NT-2 landed
  __builtin_amdgcn_s_barrier();
  CMP2(A0, B0);
  asm volatile("s_waitcnt vmcnt(0)" ::: "memory");      // tile NT-1 landed
  __builtin_amdgcn_s_barrier();
  CMP2(A1, B1);

#undef STG2
#undef CMP2

  float* dst = (KH == 2 && blockIdx.z == 1) ? scr : out;
  const int valid = c - m0;
#pragma unroll
  for (int m = 0; m < 4; ++m) {
#pragma unroll
    for (int rr = 0; rr < 4; ++rr) {
      const int tr = wr * 64 + m * 16 + lg * 4 + rr;
      if (tr < valid) {
        const int token = sorted[base + m0 + tr];
#pragma unroll
        for (int n = 0; n < 2; ++n) {
          const int col = n0 + wc * 32 + n * 16 + lr;
          float v = acc[m][n][rr];
          if (kh == 0) v += b2[e * DD + col];   // bias in kh=0 (covers KH=1 too)
          dst[(size_t)token * DD + col] = v;
        }
      }
    }
  }
}

// ---------------- split-K reduce: out += scr (bias already in kh=0 partial) ----------------
__global__ __launch_bounds__(256) void k_reduce2(float* __restrict__ out,
                                                 const float* __restrict__ scr) {
  const size_t f = (size_t)blockIdx.x * 256 + threadIdx.x;  // float4 index
  const float4 a = *reinterpret_cast<const float4*>(out + f * 4);
  const float4 b = *reinterpret_cast<const float4*>(scr + f * 4);
  float4 r;
  r.x = a.x + b.x;
  r.y = a.y + b.y;
  r.z = a.z + b.z;
  r.w = a.w + b.w;
  *reinterpret_cast<float4*>(out + f * 4) = r;
}

extern "C" void kernel_launch(void* const* d_in, const int* in_sizes, int n_in,
                              void* d_out, int out_size, void* d_ws, size_t ws_size,
                              hipStream_t stream) {
  const float* x  = (const float*)d_in[0];
  const float* Wr = (const float*)d_in[1];
  const float* br = (const float*)d_in[2];
  const float* W1 = (const float*)d_in[3];
  const float* b1 = (const float*)d_in[4];
  const float* W2 = (const float*)d_in[5];
  const float* b2 = (const float*)d_in[6];

  float* out   = (float*)d_out;
  float* probs = out + (size_t)NTOK * DD;
  float* idxf  = probs + (size_t)NTOK * EE;

  char* ws = (char*)d_ws;
  int* cnt    = (int*)(ws + 0);
  int* off    = (int*)(ws + 64);
  int* meta   = (int*)(ws + 128);      // [0]=nblk, [16..]=blk_e, [96..]=blk_m0
  int* idxi   = (int*)(ws + 1024);
  int* sorted = (int*)(ws + 33792);

  const size_t OFF_XB   = 66560;                                  // 16 MB
  const size_t OFF_W1T  = OFF_XB + (size_t)NTOK * DD * 2;         // +64 MB
  const size_t OFF_H    = OFF_W1T + (size_t)EE * DD * HH * 2;     // +64 MB
  const size_t OFF_SCR  = OFF_H + (size_t)NTOK * HH * 2;          // +32 MB
  const size_t OFF_W2TB = OFF_SCR + (size_t)NTOK * DD * 4;        // +64 MB (big path)
  const size_t NEED_SPLIT = OFF_W2TB;                              // 184,615,936
  const size_t NEED_BIG   = OFF_W2TB + (size_t)EE * DD * HH * 2;  // 251,724,800

  unsigned short* xb  = (unsigned short*)(ws + OFF_XB);
  unsigned short* W1t = (unsigned short*)(ws + OFF_W1T);
  unsigned short* h   = (unsigned short*)(ws + OFF_H);
  float*          scr = (float*)(ws + OFF_SCR);

  // FAT1: router || W1-transpose
  k_rtr1<<<NTOK / 4 + 8192, 256, 0, stream>>>(x, Wr, br, probs, idxf, idxi, xb, W1, W1t);
  k_compact<<<1, 512, 0, stream>>>(idxi, cnt, off, sorted, meta);

  if (ws_size >= NEED_BIG) {
    unsigned short* W2t = (unsigned short*)(ws + OFF_W2TB);
    // FAT2: gemm1 || W2-transpose (independent buffers)
    k_g1tr2<<<dim3(HH / 128, MAXBLK + 256), 256, 0, stream>>>(
        xb, W1t, b1, meta, cnt, off, sorted, h, W2, W2t);
    k_gemm2d<2><<<dim3(DD / 64, MAXBLK, 2), 256, 0, stream>>>(
        h, W2t, b2, meta, cnt, off, sorted, out, scr);
    k_reduce2<<<(NTOK * DD) / (256 * 4), 256, 0, stream>>>(out, scr);
  } else if (ws_size >= NEED_SPLIT) {
    unsigned short* W2t = (unsigned short*)(ws + OFF_XB);  // overlay: xb dead after gemm1
    k_g1tr2<<<dim3(HH / 128, MAXBLK), 256, 0, stream>>>(
        xb, W1t, b1, meta, cnt, off, sorted, h, W2, W2t);
    k_trcvt64<<<dim3(DD / 64, HH / 64, EE), 256, 0, stream>>>(W2, W2t, HH, DD);
    k_gemm2d<2><<<dim3(DD / 64, MAXBLK, 2), 256, 0, stream>>>(
        h, W2t, b2, meta, cnt, off, sorted, out, scr);
    k_reduce2<<<(NTOK * DD) / (256 * 4), 256, 0, stream>>>(out, scr);
  } else {
    unsigned short* W2t = (unsigned short*)(ws + OFF_XB);
    k_g1tr2<<<dim3(HH / 128, MAXBLK), 256, 0, stream>>>(
        xb, W1t, b1, meta, cnt, off, sorted, h, W2, W2t);
    k_trcvt64<<<dim3(DD / 64, HH / 64, EE), 256, 0, stream>>>(W2, W2t, HH, DD);
    k_gemm2d<1><<<dim3(DD / 64, MAXBLK, 1), 256, 0, stream>>>(
        h, W2t, b2, meta, cnt, off, sorted, out, scr);
  }
}

// Round 18
// 352.606 us; speedup vs baseline: 1.1498x; 1.0034x over previous
//
#include <hip/hip_runtime.h>

#define NTOK 8192
#define DD 1024
#define HH 4096
#define EE 8
#define MAXBLK 72

typedef __attribute__((ext_vector_type(8))) short bf16x8;
typedef __attribute__((ext_vector_type(4))) float f32x4;

__device__ __forceinline__ unsigned short f2bf(float f) {
  unsigned u = __builtin_bit_cast(unsigned, f);
  u += 0x7fffu + ((u >> 16) & 1u);  // round-to-nearest-even
  return (unsigned short)(u >> 16);
}

union Pack8 {
  unsigned short u[8];
  uint4 v;
};

__device__ __forceinline__ void gload_lds16(const void* g, void* l) {
  __builtin_amdgcn_global_load_lds(
      (const __attribute__((address_space(1))) unsigned int*)g,
      (__attribute__((address_space(3))) unsigned int*)l, 16, 0, 0);
}

// ---------------- transpose+convert body: [R][C] f32 tile -> [C][R] bf16 ----------------
__device__ __forceinline__ void trcvt_body(const float* __restrict__ src0,
                                           unsigned short* __restrict__ dst0,
                                           int R, int C, int r0, int c0,
                                           unsigned short* t) {
  const int tid = threadIdx.x;
  const float* src = src0 + (size_t)r0 * C + c0;
  unsigned short* dst = dst0 + (size_t)c0 * R + r0;
#pragma unroll
  for (int it = 0; it < 4; ++it) {
    const int r = it * 16 + (tid >> 4), c4 = (tid & 15) * 4;
    const float4 v = *reinterpret_cast<const float4*>(src + (size_t)r * C + c4);
    t[r * 66 + c4 + 0] = f2bf(v.x);
    t[r * 66 + c4 + 1] = f2bf(v.y);
    t[r * 66 + c4 + 2] = f2bf(v.z);
    t[r * 66 + c4 + 3] = f2bf(v.w);
  }
  __syncthreads();
#pragma unroll
  for (int it = 0; it < 2; ++it) {
    const int cc = it * 32 + (tid >> 3), r8 = (tid & 7) * 8;
    Pack8 p;
#pragma unroll
    for (int j = 0; j < 8; ++j) p.u[j] = t[(r8 + j) * 66 + cc];
    *reinterpret_cast<uint4*>(dst + (size_t)cc * R + r8) = p.v;
  }
}

// ---------------- FAT 1: router (blocks 0..2047) || W1 transpose (blocks 2048..10239) ----------------
__global__ __launch_bounds__(256) void k_rtr1(
    const float* __restrict__ x, const float* __restrict__ Wr,
    const float* __restrict__ br, float* __restrict__ probs,
    float* __restrict__ idxf, int* __restrict__ idxi,
    unsigned short* __restrict__ xb,
    const float* __restrict__ W1, unsigned short* __restrict__ W1t) {
  __shared__ __align__(16) unsigned short SH[64 * 66];
  const int bid = blockIdx.x;
  if (bid < NTOK / 4) {
    // ---- router + fused x->bf16 ----
    const int lane = threadIdx.x & 63;
    const int token = bid * 4 + (threadIdx.x >> 6);
    const float* xr = x + (size_t)token * DD;

    float acc[EE];
#pragma unroll
    for (int e = 0; e < EE; ++e) acc[e] = 0.f;

#pragma unroll
    for (int i = 0; i < 4; ++i) {
      const int d0 = i * 256 + lane * 4;
      const float4 xv = *reinterpret_cast<const float4*>(xr + d0);
      union { unsigned short u[4]; uint2 v; } pk;
      pk.u[0] = f2bf(xv.x); pk.u[1] = f2bf(xv.y);
      pk.u[2] = f2bf(xv.z); pk.u[3] = f2bf(xv.w);
      *reinterpret_cast<uint2*>(xb + (size_t)token * DD + d0) = pk.v;
      const float xs[4] = {xv.x, xv.y, xv.z, xv.w};
#pragma unroll
      for (int j = 0; j < 4; ++j) {
        const float xd = xs[j];
        const float4 w0 = *reinterpret_cast<const float4*>(Wr + (size_t)(d0 + j) * EE);
        const float4 w1 = *reinterpret_cast<const float4*>(Wr + (size_t)(d0 + j) * EE + 4);
        acc[0] += xd * w0.x; acc[1] += xd * w0.y; acc[2] += xd * w0.z; acc[3] += xd * w0.w;
        acc[4] += xd * w1.x; acc[5] += xd * w1.y; acc[6] += xd * w1.z; acc[7] += xd * w1.w;
      }
    }
#pragma unroll
    for (int s = 32; s > 0; s >>= 1) {
#pragma unroll
      for (int e = 0; e < EE; ++e) acc[e] += __shfl_xor(acc[e], s, 64);
    }

    float lg[EE];
#pragma unroll
    for (int e = 0; e < EE; ++e) lg[e] = acc[e] + br[e];

    int best = 0;
    float bv = lg[0];
#pragma unroll
    for (int e = 1; e < EE; ++e) {
      if (lg[e] > bv) { bv = lg[e]; best = e; }  // strict > = numpy first-max
    }
    float p[EE], s = 0.f;
#pragma unroll
    for (int e = 0; e < EE; ++e) { p[e] = expf(lg[e] - bv); s += p[e]; }
    const float inv = 1.f / s;

    if (lane == 0) {
#pragma unroll
      for (int e = 0; e < EE; ++e) probs[(size_t)token * EE + e] = p[e] * inv;
      idxf[token] = (float)best;
      idxi[token] = best;
    }
  } else {
    // ---- W1 [E][D][H] -> W1t [E][H][D] (64x64 tile) ----
    const int t = bid - NTOK / 4;          // [0, 8192)
    const int e = t >> 10;
    const int rem = t & 1023;
    const int c0 = (rem & 63) * 64;        // col in H
    const int r0 = (rem >> 6) * 64;        // row in D
    trcvt_body(W1 + (size_t)e * DD * HH, W1t + (size_t)e * DD * HH, DD, HH, r0, c0, SH);
  }
}

// ------------- Stable compaction + block table -------------
__global__ __launch_bounds__(512) void k_compact(const int* __restrict__ idxi,
                                                 int* __restrict__ cnt,
                                                 int* __restrict__ off,
                                                 int* __restrict__ sorted,
                                                 int* __restrict__ meta) {
  __shared__ int sidx[NTOK];
  __shared__ int scnt[EE], soff[EE];
  const int tid = threadIdx.x;
  for (int i = tid; i < NTOK; i += 512) sidx[i] = idxi[i];
  __syncthreads();
  const int w = tid >> 6, lane = tid & 63;
  if (w < EE) {
    int c = 0;
    for (int i = 0; i < NTOK / 64; ++i) {
      unsigned long long m = __ballot(sidx[i * 64 + lane] == w);
      c += __popcll(m);
    }
    if (lane == 0) scnt[w] = c;
  }
  __syncthreads();
  if (tid == 0) {
    int s = 0;
    for (int e = 0; e < EE; ++e) { soff[e] = s; s += scnt[e]; }
    int nb = 0;
    for (int e = 0; e < EE; ++e) {
      const int nmb = (scnt[e] + 127) >> 7;
      for (int m = 0; m < nmb; ++m) {
        meta[16 + nb] = e;
        meta[96 + nb] = m << 7;
        ++nb;
      }
    }
    meta[0] = nb;
  }
  __syncthreads();
  if (w < EE) {
    int base = soff[w];
    const unsigned long long ltmask = (1ull << lane) - 1ull;
    for (int i = 0; i < NTOK / 64; ++i) {
      const int tok = i * 64 + lane;
      const bool f = (sidx[tok] == w);
      unsigned long long m = __ballot(f);
      if (f) {
        int r = __popcll(m & ltmask);
        sorted[base + r] = tok;
      }
      base += __popcll(m);
    }
    if (lane == 0) { cnt[w] = scnt[w]; off[w] = soff[w]; }
  }
}

// ---------------- standalone transpose (fallback path for W2) ----------------
__global__ __launch_bounds__(256) void k_trcvt64(const float* __restrict__ in,
                                                 unsigned short* __restrict__ outp,
                                                 int R, int C) {
  __shared__ unsigned short t[64 * 66];
  const int e = blockIdx.z;
  trcvt_body(in + (size_t)e * R * C, outp + (size_t)e * R * C, R, C,
             blockIdx.y * 64, blockIdx.x * 64, t);
}

// ---- FAT 2: GEMM1 (y < MAXBLK) || W2 transpose (y >= MAXBLK; only when grid extends) ----
// GEMM1: h = relu(xb_sel @ W1t^T + b1) -> bf16. grid.x = HH/128 N-blocks.
__global__ __launch_bounds__(256) void k_g1tr2(
    const unsigned short* __restrict__ xb, const unsigned short* __restrict__ W1t,
    const float* __restrict__ b1, const int* __restrict__ meta,
    const int* __restrict__ cnt, const int* __restrict__ off,
    const int* __restrict__ sorted, unsigned short* __restrict__ h,
    const float* __restrict__ W2, unsigned short* __restrict__ W2t) {
  __shared__ __align__(16) unsigned short SH[2 * 128 * 64];  // 32 KB (transpose uses 8.4 KB)
  if (blockIdx.y >= MAXBLK) {
    // ---- W2 [E][H][D] -> W2t [E][D][H] (64x64 tile) ----
    const int t = (blockIdx.y - MAXBLK) * 32 + blockIdx.x;  // [0, 8192)
    const int e = t >> 10;
    const int rem = t & 1023;
    const int c0 = (rem & 15) * 64;        // col in D
    const int r0 = (rem >> 4) * 64;        // row in H
    trcvt_body(W2 + (size_t)e * HH * DD, W2t + (size_t)e * HH * DD, HH, DD, r0, c0, SH);
    return;
  }
  const int bid = blockIdx.y;
  if (bid >= meta[0]) return;
  const int e = meta[16 + bid];
  const int m0 = meta[96 + bid];
  const int c = cnt[e], base = off[e];
  const int n0 = blockIdx.x * 128;

  unsigned short* Al = SH;
  unsigned short* Bl = SH + 128 * 64;

  const int tid = threadIdx.x, l = tid & 63, w = tid >> 6;

  const unsigned short* aptr[4];
  const unsigned short* bptr[4];
  int soff4[4];
#pragma unroll
  for (int i = 0; i < 4; ++i) {
    const int r = i * 32 + w * 8 + (l >> 3);
    const int swz = ((l & 7) ^ (r & 7)) * 8;  // pre-swizzled global source
    int ar = m0 + r; if (ar >= c) ar = c - 1;
    const int tok = sorted[base + ar];
    aptr[i] = xb + (size_t)tok * DD + swz;
    bptr[i] = W1t + ((size_t)e * HH + n0 + r) * DD + swz;
    soff4[i] = r * 64 + (l & 7) * 8;
  }

  const int lr = l & 15, lg = l >> 4;
  const int wr = w >> 1, wc = w & 1;
  int aoff[4], boff[4], asw[4], bsw[4];
#pragma unroll
  for (int m = 0; m < 4; ++m) {
    int row = wr * 64 + m * 16 + lr;
    aoff[m] = row * 64; asw[m] = row & 7;
    row = wc * 64 + m * 16 + lr;
    boff[m] = row * 64; bsw[m] = row & 7;
  }

  f32x4 acc[4][4];
#pragma unroll
  for (int m = 0; m < 4; ++m)
#pragma unroll
    for (int n = 0; n < 4; ++n) acc[m][n] = {0.f, 0.f, 0.f, 0.f};

  for (int k0 = 0; k0 < DD; k0 += 64) {
    __syncthreads();
#pragma unroll
    for (int i = 0; i < 4; ++i) gload_lds16(aptr[i] + k0, &Al[soff4[i]]);
#pragma unroll
    for (int i = 0; i < 4; ++i) gload_lds16(bptr[i] + k0, &Bl[soff4[i]]);
    __syncthreads();
#pragma unroll
    for (int ks = 0; ks < 2; ++ks) {
      bf16x8 af[4], bv[4];
#pragma unroll
      for (int m = 0; m < 4; ++m)
        af[m] = *reinterpret_cast<const bf16x8*>(&Al[aoff[m] + (((ks * 4 + lg) ^ asw[m]) * 8)]);
#pragma unroll
      for (int n = 0; n < 4; ++n)
        bv[n] = *reinterpret_cast<const bf16x8*>(&Bl[boff[n] + (((ks * 4 + lg) ^ bsw[n]) * 8)]);
      __builtin_amdgcn_s_setprio(1);
#pragma unroll
      for (int m = 0; m < 4; ++m)
#pragma unroll
        for (int n = 0; n < 4; ++n)
          acc[m][n] = __builtin_amdgcn_mfma_f32_16x16x32_bf16(af[m], bv[n], acc[m][n], 0, 0, 0);
      __builtin_amdgcn_s_setprio(0);
    }
  }

  const int valid = c - m0;
#pragma unroll
  for (int m = 0; m < 4; ++m) {
#pragma unroll
    for (int rr = 0; rr < 4; ++rr) {
      const int tr = wr * 64 + m * 16 + lg * 4 + rr;
      if (tr < valid) {
        const size_t row = (size_t)(base + m0 + tr);
#pragma unroll
        for (int n = 0; n < 4; ++n) {
          const int col = n0 + wc * 64 + n * 16 + lr;
          const float v = acc[m][n][rr] + b1[e * HH + col];
          h[row * HH + col] = f2bf(fmaxf(v, 0.f));
        }
      }
    }
  }
}

// ---- GEMM2: BM=128 BN=64 BK=128 via SPLIT 64-col LDS halves (R12 geometry) + setprio ----
// 12 loads + 32 MFMA per barrier-pair; 48 KB LDS; rows 128 B stride -> 0-conflict swizzle.
// Bias added by kh==0 blocks; kh==1 writes raw partials to scr.
template <int KH>
__global__ __launch_bounds__(256) void k_gemm2s(
    const unsigned short* __restrict__ h, const unsigned short* __restrict__ W2t,
    const float* __restrict__ b2, const int* __restrict__ meta,
    const int* __restrict__ cnt, const int* __restrict__ off,
    const int* __restrict__ sorted, float* __restrict__ out,
    float* __restrict__ scr) {
  const int bid = blockIdx.y;
  if (bid >= meta[0]) return;
  const int e = meta[16 + bid];
  const int m0 = meta[96 + bid];
  const int c = cnt[e], base = off[e];
  const int n0 = blockIdx.x * 64;
  const int kh = (KH == 2) ? blockIdx.z : 0;
  const int kbase = kh * (HH / KH);

  __shared__ __align__(16) unsigned short Al0[128 * 64];
  __shared__ __align__(16) unsigned short Al1[128 * 64];
  __shared__ __align__(16) unsigned short Bl0[64 * 64];
  __shared__ __align__(16) unsigned short Bl1[64 * 64];

  const int tid = threadIdx.x, l = tid & 63, w = tid >> 6;

  const unsigned short* aptr[4];
  const unsigned short* bptr[2];
  int asoff[4], bsoff[2];
#pragma unroll
  for (int i = 0; i < 4; ++i) {
    const int r = i * 32 + w * 8 + (l >> 3);
    const int swz = ((l & 7) ^ (r & 7)) * 8;
    int ar = m0 + r; if (ar >= c) ar = c - 1;
    aptr[i] = h + (size_t)(base + ar) * HH + kbase + swz;
    asoff[i] = r * 64 + (l & 7) * 8;
  }
#pragma unroll
  for (int i = 0; i < 2; ++i) {
    const int r = i * 32 + w * 8 + (l >> 3);
    const int swz = ((l & 7) ^ (r & 7)) * 8;
    bptr[i] = W2t + ((size_t)e * DD + n0 + r) * HH + kbase + swz;
    bsoff[i] = r * 64 + (l & 7) * 8;
  }

  const int lr = l & 15, lg = l >> 4;
  const int wr = w >> 1, wc = w & 1;
  int aoff[4], boff[2], asw[4], bsw[2];
#pragma unroll
  for (int m = 0; m < 4; ++m) {
    const int row = wr * 64 + m * 16 + lr;
    aoff[m] = row * 64; asw[m] = row & 7;
  }
#pragma unroll
  for (int n = 0; n < 2; ++n) {
    const int row = wc * 32 + n * 16 + lr;
    boff[n] = row * 64; bsw[n] = row & 7;
  }

  f32x4 acc[4][2];
#pragma unroll
  for (int m = 0; m < 4; ++m)
#pragma unroll
    for (int n = 0; n < 2; ++n) acc[m][n] = {0.f, 0.f, 0.f, 0.f};

  for (int k0 = 0; k0 < HH / KH; k0 += 128) {
    __syncthreads();
#pragma unroll
    for (int i = 0; i < 4; ++i) gload_lds16(aptr[i] + k0, &Al0[asoff[i]]);
#pragma unroll
    for (int i = 0; i < 4; ++i) gload_lds16(aptr[i] + k0 + 64, &Al1[asoff[i]]);
#pragma unroll
    for (int i = 0; i < 2; ++i) gload_lds16(bptr[i] + k0, &Bl0[bsoff[i]]);
#pragma unroll
    for (int i = 0; i < 2; ++i) gload_lds16(bptr[i] + k0 + 64, &Bl1[bsoff[i]]);
    __syncthreads();
#pragma unroll
    for (int ks = 0; ks < 2; ++ks) {
      bf16x8 af[4], bv[2];
#pragma unroll
      for (int m = 0; m < 4; ++m)
        af[m] = *reinterpret_cast<const bf16x8*>(&Al0[aoff[m] + (((ks * 4 + lg) ^ asw[m]) * 8)]);
#pragma unroll
      for (int n = 0; n < 2; ++n)
        bv[n] = *reinterpret_cast<const bf16x8*>(&Bl0[boff[n] + (((ks * 4 + lg) ^ bsw[n]) * 8)]);
      __builtin_amdgcn_s_setprio(1);
#pragma unroll
      for (int m = 0; m < 4; ++m)
#pragma unroll
        for (int n = 0; n < 2; ++n)
          acc[m][n] = __builtin_amdgcn_mfma_f32_16x16x32_bf16(af[m], bv[n], acc[m][n], 0, 0, 0);
      __builtin_amdgcn_s_setprio(0);
    }
#pragma unroll
    for (int ks = 0; ks < 2; ++ks) {
      bf16x8 af[4], bv[2];
#pragma unroll
      for (int m = 0; m < 4; ++m)
        af[m] = *reinterpret_cast<const bf16x8*>(&Al1[aoff[m] + (((ks * 4 + lg) ^ asw[m]) * 8)]);
#pragma unroll
      for (int n = 0; n < 2; ++n)
        bv[n] = *reinterpret_cast<const bf16x8*>(&Bl1[boff[n] + (((ks * 4 + lg) ^ bsw[n]) * 8)]);
      __builtin_amdgcn_s_setprio(1);
#pragma unroll
      for (int m = 0; m < 4; ++m)
#pragma unroll
        for (int n = 0; n < 2; ++n)
          acc[m][n] = __builtin_amdgcn_mfma_f32_16x16x32_bf16(af[m], bv[n], acc[m][n], 0, 0, 0);
      __builtin_amdgcn_s_setprio(0);
    }
  }

  float* dst = (KH == 2 && blockIdx.z == 1) ? scr : out;
  const int valid = c - m0;
#pragma unroll
  for (int m = 0; m < 4; ++m) {
#pragma unroll
    for (int rr = 0; rr < 4; ++rr) {
      const int tr = wr * 64 + m * 16 + lg * 4 + rr;
      if (tr < valid) {
        const int token = sorted[base + m0 + tr];
#pragma unroll
        for (int n = 0; n < 2; ++n) {
          const int col = n0 + wc * 32 + n * 16 + lr;
          float v = acc[m][n][rr];
          if (kh == 0) v += b2[e * DD + col];   // bias in kh=0 (covers KH=1 too)
          dst[(size_t)token * DD + col] = v;
        }
      }
    }
  }
}

// ---------------- split-K reduce: out += scr (bias already in kh=0 partial) ----------------
__global__ __launch_bounds__(256) void k_reduce2(float* __restrict__ out,
                                                 const float* __restrict__ scr) {
  const size_t f = (size_t)blockIdx.x * 256 + threadIdx.x;  // float4 index
  const float4 a = *reinterpret_cast<const float4*>(out + f * 4);
  const float4 b = *reinterpret_cast<const float4*>(scr + f * 4);
  float4 r;
  r.x = a.x + b.x;
  r.y = a.y + b.y;
  r.z = a.z + b.z;
  r.w = a.w + b.w;
  *reinterpret_cast<float4*>(out + f * 4) = r;
}

extern "C" void kernel_launch(void* const* d_in, const int* in_sizes, int n_in,
                              void* d_out, int out_size, void* d_ws, size_t ws_size,
                              hipStream_t stream) {
  const float* x  = (const float*)d_in[0];
  const float* Wr = (const float*)d_in[1];
  const float* br = (const float*)d_in[2];
  const float* W1 = (const float*)d_in[3];
  const float* b1 = (const float*)d_in[4];
  const float* W2 = (const float*)d_in[5];
  const float* b2 = (const float*)d_in[6];

  float* out   = (float*)d_out;
  float* probs = out + (size_t)NTOK * DD;
  float* idxf  = probs + (size_t)NTOK * EE;

  char* ws = (char*)d_ws;
  int* cnt    = (int*)(ws + 0);
  int* off    = (int*)(ws + 64);
  int* meta   = (int*)(ws + 128);      // [0]=nblk, [16..]=blk_e, [96..]=blk_m0
  int* idxi   = (int*)(ws + 1024);
  int* sorted = (int*)(ws + 33792);

  const size_t OFF_XB   = 66560;                                  // 16 MB
  const size_t OFF_W1T  = OFF_XB + (size_t)NTOK * DD * 2;         // +64 MB
  const size_t OFF_H    = OFF_W1T + (size_t)EE * DD * HH * 2;     // +64 MB
  const size_t OFF_SCR  = OFF_H + (size_t)NTOK * HH * 2;          // +32 MB
  const size_t OFF_W2TB = OFF_SCR + (size_t)NTOK * DD * 4;        // +64 MB (big path)
  const size_t NEED_SPLIT = OFF_W2TB;                              // 184,615,936
  const size_t NEED_BIG   = OFF_W2TB + (size_t)EE * DD * HH * 2;  // 251,724,800

  unsigned short* xb  = (unsigned short*)(ws + OFF_XB);
  unsigned short* W1t = (unsigned short*)(ws + OFF_W1T);
  unsigned short* h   = (unsigned short*)(ws + OFF_H);
  float*          scr = (float*)(ws + OFF_SCR);

  // FAT1: router || W1-transpose
  k_rtr1<<<NTOK / 4 + 8192, 256, 0, stream>>>(x, Wr, br, probs, idxf, idxi, xb, W1, W1t);
  k_compact<<<1, 512, 0, stream>>>(idxi, cnt, off, sorted, meta);

  if (ws_size >= NEED_BIG) {
    unsigned short* W2t = (unsigned short*)(ws + OFF_W2TB);
    // FAT2: gemm1 || W2-transpose (independent buffers)
    k_g1tr2<<<dim3(HH / 128, MAXBLK + 256), 256, 0, stream>>>(
        xb, W1t, b1, meta, cnt, off, sorted, h, W2, W2t);
    k_gemm2s<2><<<dim3(DD / 64, MAXBLK, 2), 256, 0, stream>>>(
        h, W2t, b2, meta, cnt, off, sorted, out, scr);
    k_reduce2<<<(NTOK * DD) / (256 * 4), 256, 0, stream>>>(out, scr);
  } else if (ws_size >= NEED_SPLIT) {
    unsigned short* W2t = (unsigned short*)(ws + OFF_XB);  // overlay: xb dead after gemm1
    k_g1tr2<<<dim3(HH / 128, MAXBLK), 256, 0, stream>>>(
        xb, W1t, b1, meta, cnt, off, sorted, h, W2, W2t);
    k_trcvt64<<<dim3(DD / 64, HH / 64, EE), 256, 0, stream>>>(W2, W2t, HH, DD);
    k_gemm2s<2><<<dim3(DD / 64, MAXBLK, 2), 256, 0, stream>>>(
        h, W2t, b2, meta, cnt, off, sorted, out, scr);
    k_reduce2<<<(NTOK * DD) / (256 * 4), 256, 0, stream>>>(out, scr);
  } else {
    unsigned short* W2t = (unsigned short*)(ws + OFF_XB);
    k_g1tr2<<<dim3(HH / 128, MAXBLK), 256, 0, stream>>>(
        xb, W1t, b1, meta, cnt, off, sorted, h, W2, W2t);
    k_trcvt64<<<dim3(DD / 64, HH / 64, EE), 256, 0, stream>>>(W2, W2t, HH, DD);
    k_gemm2s<1><<<dim3(DD / 64, MAXBLK, 1), 256, 0, stream>>>(
        h, W2t, b2, meta, cnt, off, sorted, out, scr);
  }
}